// Round 1
// baseline (462.318 us; speedup 1.0000x reference)
//
#include <hip/hip_runtime.h>
#include <cstdint>
#include <cstddef>

#define PAD_IDX 200000
#define KN 50

using frag8 = __attribute__((ext_vector_type(8))) short;
using f32x4 = __attribute__((ext_vector_type(4))) float;

__device__ __forceinline__ short f2bf(float v) {
    union { float f; uint32_t u; } x; x.f = v;
    uint32_t r = (x.u + 0x7fffu + ((x.u >> 16) & 1u)) >> 16;
    return (short)(uint16_t)r;
}
__device__ __forceinline__ float bf2f(short s) {
    union { uint32_t u; float f; } x; x.u = ((uint32_t)(uint16_t)s) << 16;
    return x.f;
}
__device__ __forceinline__ float sigm(float x) { return 1.f / (1.f + __expf(-x)); }

// ---------------- prep kernels ----------------

__global__ void k_cast_bf16(const float* __restrict__ src, short* __restrict__ dst, int n) {
    int i = blockIdx.x * 256 + threadIdx.x;
    if (i < n) dst[i] = f2bf(src[i]);
}

// Bmat[n][k] (256x128): n<128 -> gcn_W[n][k] ; n>=128 -> gcn_W[n-128][128+k]
// bias256[n]: 0 for n<128, lin_b+b for n>=128
__global__ void k_build_bmat(const float* __restrict__ gcn_W, const float* __restrict__ lin_b,
                             const float* __restrict__ gb, short* __restrict__ Bmat,
                             float* __restrict__ bias256) {
    int i = blockIdx.x * 256 + threadIdx.x;
    if (i < 256 * 128) {
        int n = i >> 7, k = i & 127;
        float v = (n < 128) ? gcn_W[n * 256 + k] : gcn_W[(n - 128) * 256 + 128 + k];
        Bmat[i] = f2bf(v);
        if (k == 0) bias256[n] = (n < 128) ? 0.f : (lin_b[n - 128] + gb[n - 128]);
    }
}

// Bcomb[n][k] (2048x512): k<256 -> Wih[n][k] ; else Whh[n][k-256]  (Whh ld=512)
__global__ void k_build_bcomb(const float* __restrict__ Wih, const float* __restrict__ Whh,
                              short* __restrict__ Bcomb) {
    int i = blockIdx.x * 256 + threadIdx.x;
    if (i < 2048 * 512) {
        int n = i >> 9, k = i & 511;
        float v = (k < 256) ? Wih[n * 256 + k] : Whh[(size_t)n * 512 + (k - 256)];
        Bcomb[i] = f2bf(v);
    }
}

// ---------------- generic MFMA GEMM: C[m,n] = sum_k A[m,k]*B[n,k] (+bias[n]) ----------------

constexpr int SA = 40;  // LDS row stride in shorts (padded: 80B -> ~2-way, free)

template<bool RELU, bool OUTBF, typename AT>
__global__ __launch_bounds__(256) void gemm_bt(
    const AT* __restrict__ A, int lda, const short* __restrict__ B, int ldb,
    float* __restrict__ C, short* __restrict__ Cbf, int ldc,
    const float* __restrict__ bias, int M, int N, int K)
{
    __shared__ short As[128 * SA];
    __shared__ short Bs[128 * SA];
    const int t = threadIdx.x;
    const int m0 = blockIdx.y * 128, n0 = blockIdx.x * 128;
    const int wave = t >> 6, lane = t & 63;
    const int wr = wave >> 1, wc = wave & 1;
    f32x4 acc[4][4] = {};
    for (int k0 = 0; k0 < K; k0 += 32) {
#pragma unroll
        for (int i = 0; i < 2; ++i) {
            int idx = t + i * 256;
            int r = idx >> 2, c8 = (idx & 3) << 3;
            frag8 av = {0, 0, 0, 0, 0, 0, 0, 0};
            int arow = m0 + r;
            if (arow < M) {
                if constexpr (sizeof(AT) == 2) {
                    av = *reinterpret_cast<const frag8*>((const short*)A + (size_t)arow * lda + k0 + c8);
                } else {
                    const float* p = (const float*)A + (size_t)arow * lda + k0 + c8;
#pragma unroll
                    for (int j = 0; j < 8; ++j) av[j] = f2bf(p[j]);
                }
            }
            *reinterpret_cast<frag8*>(&As[r * SA + c8]) = av;
            frag8 bv = *reinterpret_cast<const frag8*>(B + (size_t)(n0 + r) * ldb + k0 + c8);
            *reinterpret_cast<frag8*>(&Bs[r * SA + c8]) = bv;
        }
        __syncthreads();
        frag8 af[4], bfv[4];
#pragma unroll
        for (int f = 0; f < 4; ++f) {
            af[f]  = *reinterpret_cast<const frag8*>(&As[(wr * 64 + f * 16 + (lane & 15)) * SA + ((lane >> 4) << 3)]);
            bfv[f] = *reinterpret_cast<const frag8*>(&Bs[(wc * 64 + f * 16 + (lane & 15)) * SA + ((lane >> 4) << 3)]);
        }
#pragma unroll
        for (int fm = 0; fm < 4; ++fm)
#pragma unroll
            for (int fn = 0; fn < 4; ++fn)
                acc[fm][fn] = __builtin_amdgcn_mfma_f32_16x16x32_bf16(af[fm], bfv[fn], acc[fm][fn], 0, 0, 0);
        __syncthreads();
    }
#pragma unroll
    for (int fm = 0; fm < 4; ++fm) {
        int rowb = m0 + wr * 64 + fm * 16 + ((lane >> 4) << 2);
#pragma unroll
        for (int fn = 0; fn < 4; ++fn) {
            int col = n0 + wc * 64 + fn * 16 + (lane & 15);
            float bc = bias[col];
#pragma unroll
            for (int j = 0; j < 4; ++j) {
                int rr = rowb + j;
                if (rr < M) {
                    float v = acc[fm][fn][j] + bc;
                    if (RELU) v = fmaxf(v, 0.f);
                    if (OUTBF) Cbf[(size_t)rr * ldc + col] = f2bf(v);
                    else       C[(size_t)rr * ldc + col] = v;
                }
            }
        }
    }
}

// ---------------- neigh (GCN attention + gate) ----------------
// one block (128 threads) per row; T is bf16 table (200001 x 256): [projRel | projEnt+bias]

__global__ __launch_bounds__(128) void k_neigh(
    const int* __restrict__ conns, const int* __restrict__ deg,
    const int* __restrict__ ids2, int side,
    const float* __restrict__ emb, const short* __restrict__ T,
    const float* __restrict__ cg_W1, const float* __restrict__ cg_b1,
    const float* __restrict__ cg_ln_g, const float* __restrict__ cg_ln_b,
    const float* __restrict__ cg_W2, const float* __restrict__ cg_b2,
    const float* __restrict__ temp_p,
    float* __restrict__ outv, short* __restrict__ outbf,
    int out_row_off)
{
    int n = blockIdx.x;
    int t = threadIdx.x;  // 128
    __shared__ float proj[KN * 129];
    __shared__ float se[128];
    __shared__ int rels[KN], ents[KN];
    __shared__ float wts[KN];
    __shared__ float aggs[128];
    __shared__ float gate_s;

    int self_id = ids2[n * 2 + side];
    float self_e = emb[(size_t)self_id * 128 + t];
    se[t] = self_e;
    if (t < KN) {
        rels[t] = conns[((size_t)n * KN + t) * 2];
        ents[t] = conns[((size_t)n * KN + t) * 2 + 1];
    }
    __syncthreads();

#pragma unroll 2
    for (int k = 0; k < KN; ++k) {
        int r = rels[k], e = ents[k];
        float raw = bf2f(T[(size_t)r * 256 + t]) + bf2f(T[(size_t)e * 256 + 128 + t]);
        float p = raw > 0.f ? raw : 0.01f * raw;
        proj[k * 129 + t] = p;
    }
    __syncthreads();

    float sc = -1e9f;
    if (t < KN) {
        float s = 0.f;
        const float* pr = &proj[t * 129];
        for (int d = 0; d < 128; ++d) s += pr[d] * se[d];
        sc = (rels[t] == PAD_IDX) ? -1e9f : s;
    }
    if (t < 64) {
        float m = sc;
        for (int o = 32; o; o >>= 1) m = fmaxf(m, __shfl_xor(m, o));
        float e = (t < KN) ? __expf(sc - m) : 0.f;
        float ssum = e;
        for (int o = 32; o; o >>= 1) ssum += __shfl_xor(ssum, o);
        if (t < KN) wts[t] = e / ssum;
    }
    __syncthreads();

    float agg = 0.f;
    for (int k = 0; k < KN; ++k) agg += wts[k] * proj[k * 129 + t];
    aggs[t] = agg;
    __syncthreads();

    if (t < 64) {
        const float* w1 = cg_W1 + t * 128;
        float acc = cg_b1[t];
        for (int d = 0; d < 128; ++d) acc += aggs[d] * w1[d];
        float s = acc;
        for (int o = 32; o; o >>= 1) s += __shfl_xor(s, o);
        float mean = s * (1.f / 64.f);
        float dv = acc - mean;
        float vs = dv * dv;
        for (int o = 32; o; o >>= 1) vs += __shfl_xor(vs, o);
        float var = vs * (1.f / 64.f);
        float hv = dv * rsqrtf(var + 1e-5f) * cg_ln_g[t] + cg_ln_b[t];
        hv = fmaxf(hv, 0.f);
        float lg = hv * cg_W2[t];
        for (int o = 32; o; o >>= 1) lg += __shfl_xor(lg, o);
        if (t == 0) {
            lg += cg_b2[0];
            float temp = fminf(fmaxf(temp_p[0], 0.1f), 5.0f);
            float gate = sigm(lg / temp);
            gate_s = (deg[n] > 0) ? gate : 0.f;
        }
    }
    __syncthreads();

    float o = tanhf(self_e + gate_s * agg);
    size_t off = (size_t)(out_row_off + n) * 256 + (size_t)side * 128 + t;
    outv[off] = o;
    outbf[off] = f2bf(o);
}

// ---------------- LN (+residual) for support_enc ----------------
// enc = LN(se2out + x); rows<4096 also write bf16 into AH[:, 0:256]

__global__ void k_ln(const float* __restrict__ se2out, const float* __restrict__ x,
                     const float* __restrict__ g, const float* __restrict__ b,
                     float* __restrict__ enc, short* __restrict__ AH, int M) {
    int wave = threadIdx.x >> 6, lane = threadIdx.x & 63;
    int row = blockIdx.x * 4 + wave;
    if (row >= M) return;
    const float* pr = se2out + (size_t)row * 256;
    const float* px = x + (size_t)row * 256;
    float v[4];
    float s = 0.f;
#pragma unroll
    for (int i = 0; i < 4; ++i) { v[i] = pr[lane + 64 * i] + px[lane + 64 * i]; s += v[i]; }
    for (int o = 32; o; o >>= 1) s += __shfl_xor(s, o);
    float mean = s * (1.f / 256.f);
    float vs = 0.f;
#pragma unroll
    for (int i = 0; i < 4; ++i) { float d = v[i] - mean; vs += d * d; }
    for (int o = 32; o; o >>= 1) vs += __shfl_xor(vs, o);
    float inv = rsqrtf(vs * (1.f / 256.f) + 1e-5f);
#pragma unroll
    for (int i = 0; i < 4; ++i) {
        int col = lane + 64 * i;
        float ov = (v[i] - mean) * inv * g[col] + b[col];
        enc[(size_t)row * 256 + col] = ov;
        if (row < 4096) AH[(size_t)row * 512 + col] = f2bf(ov);
    }
}

__global__ void k_supportg(const float* __restrict__ enc, float* __restrict__ gout) {
    int j = threadIdx.x;  // 256
    float s = 0.f;
    for (int i = 0; i < 5; ++i) s += enc[(size_t)(4096 + i) * 256 + j];
    gout[j] = s * 0.2f;
}

// whh_r[n] = sum_j g[j]*Whh[n][256+j]; bias_a = bih+bhh; bias_b = bias_a + whh_r
__global__ void k_whhbias(const float* __restrict__ gvec, const float* __restrict__ Whh,
                          const float* __restrict__ bih, const float* __restrict__ bhh,
                          float* __restrict__ bias_a, float* __restrict__ bias_b) {
    int n = blockIdx.x * 256 + threadIdx.x;
    if (n < 2048) {
        const float* wr = Whh + (size_t)n * 512 + 256;
        float s = 0.f;
        for (int j = 0; j < 256; ++j) s += gvec[j] * wr[j];
        float ba = bih[n] + bhh[n];
        bias_a[n] = ba;
        bias_b[n] = ba + s;
    }
}

// LSTM elementwise: gates (4096x2048 f32, [i|f|g|o]) -> c, h; h also bf16 into AH[:,256:512]
__global__ void k_lstm_ew(const float* __restrict__ gates, float* __restrict__ c,
                          const float* __restrict__ qenc, float* __restrict__ h,
                          short* __restrict__ AH) {
    int idx = blockIdx.x * 256 + threadIdx.x;  // 4096*512
    int n = idx >> 9, j = idx & 511;
    const float* gp = gates + (size_t)n * 2048;
    float gi = gp[j], gf = gp[512 + j], gg = gp[1024 + j], go = gp[1536 + j];
    float cn = sigm(gf) * c[idx] + sigm(gi) * tanhf(gg);
    c[idx] = cn;
    float hc = sigm(go) * tanhf(cn);
    if (j < 256) {
        float hv = qenc[(size_t)n * 256 + j] + hc;
        h[(size_t)n * 256 + j] = hv;
        AH[(size_t)n * 512 + 256 + j] = f2bf(hv);
    }
}

__global__ void k_dot(const float* __restrict__ h, const float* __restrict__ gvec,
                      float* __restrict__ out) {
    int wave = threadIdx.x >> 6, lane = threadIdx.x & 63;
    int n = blockIdx.x * 4 + wave;
    if (n >= 4096) return;
    const float* p = h + (size_t)n * 256;
    float s = 0.f;
#pragma unroll
    for (int i = 0; i < 4; ++i) s += p[lane + 64 * i] * gvec[lane + 64 * i];
    for (int o = 32; o; o >>= 1) s += __shfl_xor(s, o);
    if (!lane) out[n] = s;
}

// ---------------- launch ----------------

extern "C" void kernel_launch(void* const* d_in, const int* in_sizes, int n_in,
                              void* d_out, int out_size, void* d_ws, size_t ws_size,
                              hipStream_t stream) {
    const int* query     = (const int*)d_in[0];
    const int* support   = (const int*)d_in[1];
    const int* q_l1      = (const int*)d_in[2];
    const int* q_deg_l   = (const int*)d_in[3];
    const int* q_r1      = (const int*)d_in[4];
    const int* q_deg_r   = (const int*)d_in[5];
    const int* s_l1      = (const int*)d_in[6];
    const int* s_deg_l   = (const int*)d_in[7];
    const int* s_r1      = (const int*)d_in[8];
    const int* s_deg_r   = (const int*)d_in[9];
    const float* emb     = (const float*)d_in[10];
    const float* gcn_W   = (const float*)d_in[11];
    const float* gcn_lin_b = (const float*)d_in[12];
    const float* gcn_b   = (const float*)d_in[13];
    const float* gate_temp = (const float*)d_in[14];
    const float* cg_W1   = (const float*)d_in[15];
    const float* cg_b1   = (const float*)d_in[16];
    const float* cg_ln_g = (const float*)d_in[17];
    const float* cg_ln_b = (const float*)d_in[18];
    const float* cg_W2   = (const float*)d_in[19];
    const float* cg_b2   = (const float*)d_in[20];
    const float* se_W1   = (const float*)d_in[21];
    const float* se_b1   = (const float*)d_in[22];
    const float* se_W2   = (const float*)d_in[23];
    const float* se_b2   = (const float*)d_in[24];
    const float* se_ln_g = (const float*)d_in[25];
    const float* se_ln_b = (const float*)d_in[26];
    const float* lstm_Wih = (const float*)d_in[27];
    const float* lstm_Whh = (const float*)d_in[28];
    const float* lstm_bih = (const float*)d_in[29];
    const float* lstm_bhh = (const float*)d_in[30];

    char* ws = (char*)d_ws;
    // big overlay region: T (neigh phase) then post-neigh buffers
    short* T       = (short*)(ws + 0);              // 200001*256*2 = 102,400,512
    short* h1bf    = (short*)(ws + 0);              // 4101*512*2
    float* se2out  = (float*)(ws + 4199424);        // 4101*256*4
    float* enc     = (float*)(ws + 8398848);        // 4101*256*4
    float* gates   = (float*)(ws + 12598272);       // 4096*2048*4
    float* cbuf    = (float*)(ws + 46152704);       // 4096*512*4
    float* hbuf    = (float*)(ws + 54541312);       // 4096*256*4
    short* AH      = (short*)(ws + 58735616);       // 4096*512*2
    // persistent region after the table
    float* qsvec   = (float*)(ws + 102400512);      // 4101*256*4
    short* qsbf    = (short*)(ws + 106599936);      // 4101*256*2
    short* Bmat    = (short*)(ws + 108699648);      // 256*128*2
    float* bias256 = (float*)(ws + 108765184);      // 1024
    short* sw1     = (short*)(ws + 108766208);      // 512*256*2
    short* sw2     = (short*)(ws + 109028352);      // 256*512*2
    short* Bcomb   = (short*)(ws + 109290496);      // 2048*512*2
    float* sg      = (float*)(ws + 111387648);      // 256*4
    float* bias_a  = (float*)(ws + 111388672);      // 2048*4
    float* bias_b  = (float*)(ws + 111396864);      // 2048*4
    float* outp    = (float*)d_out;

    hipMemsetAsync(AH, 0, (size_t)4096 * 512 * 2, stream);
    hipMemsetAsync(cbuf, 0, (size_t)4096 * 512 * 4, stream);

    k_cast_bf16<<<512, 256, 0, stream>>>(se_W1, sw1, 512 * 256);
    k_cast_bf16<<<512, 256, 0, stream>>>(se_W2, sw2, 256 * 512);
    k_build_bmat<<<128, 256, 0, stream>>>(gcn_W, gcn_lin_b, gcn_b, Bmat, bias256);
    k_build_bcomb<<<4096, 256, 0, stream>>>(lstm_Wih, lstm_Whh, Bcomb);

    // T = emb @ [W1|W2]^T + bias256   (M=200001, N=256, K=128)
    gemm_bt<false, true, float><<<dim3(2, 1563), 256, 0, stream>>>(
        emb, 128, Bmat, 128, nullptr, T, 256, bias256, 200001, 256, 128);

    // neigh: q left/right, s left/right
    k_neigh<<<4096, 128, 0, stream>>>(q_l1, q_deg_l, query, 0, emb, T,
        cg_W1, cg_b1, cg_ln_g, cg_ln_b, cg_W2, cg_b2, gate_temp, qsvec, qsbf, 0);
    k_neigh<<<4096, 128, 0, stream>>>(q_r1, q_deg_r, query, 1, emb, T,
        cg_W1, cg_b1, cg_ln_g, cg_ln_b, cg_W2, cg_b2, gate_temp, qsvec, qsbf, 0);
    k_neigh<<<5, 128, 0, stream>>>(s_l1, s_deg_l, support, 0, emb, T,
        cg_W1, cg_b1, cg_ln_g, cg_ln_b, cg_W2, cg_b2, gate_temp, qsvec, qsbf, 4096);
    k_neigh<<<5, 128, 0, stream>>>(s_r1, s_deg_r, support, 1, emb, T,
        cg_W1, cg_b1, cg_ln_g, cg_ln_b, cg_W2, cg_b2, gate_temp, qsvec, qsbf, 4096);

    // support_enc: h1 = relu(x@W1^T+b1) ; se2out = h1@W2^T+b2 ; enc = LN(se2out + x)
    gemm_bt<true, true, short><<<dim3(4, 33), 256, 0, stream>>>(
        qsbf, 256, sw1, 256, nullptr, h1bf, 512, se_b1, 4101, 512, 256);
    gemm_bt<false, false, short><<<dim3(2, 33), 256, 0, stream>>>(
        h1bf, 512, sw2, 512, se2out, nullptr, 256, se_b2, 4101, 256, 512);
    k_ln<<<1026, 256, 0, stream>>>(se2out, qsvec, se_ln_g, se_ln_b, enc, AH, 4101);

    k_supportg<<<1, 256, 0, stream>>>(enc, sg);
    k_whhbias<<<8, 256, 0, stream>>>(sg, lstm_Whh, lstm_bih, lstm_bhh, bias_a, bias_b);

    // 4 LSTM steps: gates = [qenc | h] @ [Wih | WhhA]^T + bias(step)
    for (int s = 0; s < 4; ++s) {
        gemm_bt<false, false, short><<<dim3(16, 32), 256, 0, stream>>>(
            AH, 512, Bcomb, 512, gates, nullptr, 2048, s ? bias_b : bias_a, 4096, 2048, 512);
        k_lstm_ew<<<8192, 256, 0, stream>>>(gates, cbuf, enc, hbuf, AH);
    }

    k_dot<<<1024, 256, 0, stream>>>(hbuf, sg, outp);
}

// Round 2
// 426.123 us; speedup vs baseline: 1.0849x; 1.0849x over previous
//
#include <hip/hip_runtime.h>
#include <cstdint>
#include <cstddef>

#define PAD_IDX 200000
#define KN 50

using frag8 = __attribute__((ext_vector_type(8))) short;
using f32x4 = __attribute__((ext_vector_type(4))) float;

__device__ __forceinline__ short f2bf(float v) {
    union { float f; uint32_t u; } x; x.f = v;
    uint32_t r = (x.u + 0x7fffu + ((x.u >> 16) & 1u)) >> 16;
    return (short)(uint16_t)r;
}
__device__ __forceinline__ float bf2f(short s) {
    union { uint32_t u; float f; } x; x.u = ((uint32_t)(uint16_t)s) << 16;
    return x.f;
}
__device__ __forceinline__ float sigm(float x) { return 1.f / (1.f + __expf(-x)); }

// ---------------- prep kernels ----------------

__global__ void k_cast_bf16(const float* __restrict__ src, short* __restrict__ dst, int n) {
    int i = blockIdx.x * 256 + threadIdx.x;
    if (i < n) dst[i] = f2bf(src[i]);
}

__global__ void k_build_bmat(const float* __restrict__ gcn_W, const float* __restrict__ lin_b,
                             const float* __restrict__ gb, short* __restrict__ Bmat,
                             float* __restrict__ bias256) {
    int i = blockIdx.x * 256 + threadIdx.x;
    if (i < 256 * 128) {
        int n = i >> 7, k = i & 127;
        float v = (n < 128) ? gcn_W[n * 256 + k] : gcn_W[(n - 128) * 256 + 128 + k];
        Bmat[i] = f2bf(v);
        if (k == 0) bias256[n] = (n < 128) ? 0.f : (lin_b[n - 128] + gb[n - 128]);
    }
}

// permuted Bcomb: col c = 64u+16g+v  <->  orig LSTM row n = 512*g + 16u + v
__device__ __forceinline__ int lstm_perm(int c) {
    int u = c >> 6, g = (c >> 4) & 3, v = c & 15;
    return (g << 9) + (u << 4) + v;
}

__global__ void k_build_bcomb(const float* __restrict__ Wih, const float* __restrict__ Whh,
                              short* __restrict__ Bcomb) {
    int i = blockIdx.x * 256 + threadIdx.x;
    if (i < 2048 * 512) {
        int c = i >> 9, k = i & 511;
        int n = lstm_perm(c);
        float v = (k < 256) ? Wih[n * 256 + k] : Whh[(size_t)n * 512 + (k - 256)];
        Bcomb[i] = f2bf(v);
    }
}

// ---------------- generic MFMA GEMM: C[m,n] = sum_k A[m,k]*B[n,k] (+bias[n]) ----------------

constexpr int SA = 40;   // LDS row stride (shorts) for staging
constexpr int CS = 132;  // LDS row stride (shorts) for C bounce

template<bool RELU, bool OUTBF, typename AT>
__global__ __launch_bounds__(256) void gemm_bt(
    const AT* __restrict__ A, int lda, const short* __restrict__ B, int ldb,
    float* __restrict__ C, short* __restrict__ Cbf, int ldc,
    const float* __restrict__ bias, int M, int N, int K)
{
    __shared__ short sh[2 * 128 * SA];
    short* As = sh;
    short* Bs = sh + 128 * SA;
    const int t = threadIdx.x;
    const int m0 = blockIdx.y * 128, n0 = blockIdx.x * 128;
    const int wave = t >> 6, lane = t & 63;
    const int wr = wave >> 1, wc = wave & 1;
    f32x4 acc[4][4] = {};
    for (int k0 = 0; k0 < K; k0 += 32) {
#pragma unroll
        for (int i = 0; i < 2; ++i) {
            int idx = t + i * 256;
            int r = idx >> 2, c8 = (idx & 3) << 3;
            frag8 av = {0, 0, 0, 0, 0, 0, 0, 0};
            int arow = m0 + r;
            if (arow < M) {
                if constexpr (sizeof(AT) == 2) {
                    av = *reinterpret_cast<const frag8*>((const short*)A + (size_t)arow * lda + k0 + c8);
                } else {
                    const float* p = (const float*)A + (size_t)arow * lda + k0 + c8;
                    float4 v0 = *reinterpret_cast<const float4*>(p);
                    float4 v1 = *reinterpret_cast<const float4*>(p + 4);
                    av[0] = f2bf(v0.x); av[1] = f2bf(v0.y); av[2] = f2bf(v0.z); av[3] = f2bf(v0.w);
                    av[4] = f2bf(v1.x); av[5] = f2bf(v1.y); av[6] = f2bf(v1.z); av[7] = f2bf(v1.w);
                }
            }
            *reinterpret_cast<frag8*>(&As[r * SA + c8]) = av;
            frag8 bv = *reinterpret_cast<const frag8*>(B + (size_t)(n0 + r) * ldb + k0 + c8);
            *reinterpret_cast<frag8*>(&Bs[r * SA + c8]) = bv;
        }
        __syncthreads();
        frag8 af[4], bfv[4];
#pragma unroll
        for (int f = 0; f < 4; ++f) {
            af[f]  = *reinterpret_cast<const frag8*>(&As[(wr * 64 + f * 16 + (lane & 15)) * SA + ((lane >> 4) << 3)]);
            bfv[f] = *reinterpret_cast<const frag8*>(&Bs[(wc * 64 + f * 16 + (lane & 15)) * SA + ((lane >> 4) << 3)]);
        }
#pragma unroll
        for (int fm = 0; fm < 4; ++fm)
#pragma unroll
            for (int fn = 0; fn < 4; ++fn)
                acc[fm][fn] = __builtin_amdgcn_mfma_f32_16x16x32_bf16(af[fm], bfv[fn], acc[fm][fn], 0, 0, 0);
        __syncthreads();
    }

    if constexpr (OUTBF) {
        // LDS bounce: two 64-row halves, then coalesced dwordx4 stores
#pragma unroll
        for (int half = 0; half < 2; ++half) {
            if (wr == half) {
#pragma unroll
                for (int fm = 0; fm < 4; ++fm) {
                    int rl = fm * 16 + ((lane >> 4) << 2);
#pragma unroll
                    for (int fn = 0; fn < 4; ++fn) {
                        int col = wc * 64 + fn * 16 + (lane & 15);
                        float bc = bias[n0 + col];
#pragma unroll
                        for (int j = 0; j < 4; ++j) {
                            float v = acc[fm][fn][j] + bc;
                            if (RELU) v = fmaxf(v, 0.f);
                            sh[(rl + j) * CS + col] = f2bf(v);
                        }
                    }
                }
            }
            __syncthreads();
#pragma unroll
            for (int p = 0; p < 4; ++p) {
                int off16 = p * 256 + t;
                int rl = off16 >> 4, ch = off16 & 15;
                int rr = m0 + half * 64 + rl;
                if (rr < M) {
                    frag8 val = *reinterpret_cast<const frag8*>(&sh[rl * CS + ch * 8]);
                    *reinterpret_cast<frag8*>(&Cbf[(size_t)rr * ldc + n0 + ch * 8]) = val;
                }
            }
            __syncthreads();
        }
    } else {
#pragma unroll
        for (int fm = 0; fm < 4; ++fm) {
            int rowb = m0 + wr * 64 + fm * 16 + ((lane >> 4) << 2);
#pragma unroll
            for (int fn = 0; fn < 4; ++fn) {
                int col = n0 + wc * 64 + fn * 16 + (lane & 15);
                float bc = bias[col];
#pragma unroll
                for (int j = 0; j < 4; ++j) {
                    int rr = rowb + j;
                    if (rr < M) {
                        float v = acc[fm][fn][j] + bc;
                        if (RELU) v = fmaxf(v, 0.f);
                        C[(size_t)rr * ldc + col] = v;
                    }
                }
            }
        }
    }
}

// ---------------- fused LSTM-step GEMM ----------------
// gates(permuted cols) = AHcur @ Bcomb2^T + bias2 ; epilogue does the cell update.
// A: 4096x512 bf16, B: 2048x512 bf16, grid (16, 32).

__global__ __launch_bounds__(256) void gemm_lstm(
    const short* __restrict__ A, const short* __restrict__ B,
    const float* __restrict__ bias2, float* __restrict__ cbuf,
    const float* __restrict__ enc, float* __restrict__ hbuf,
    short* __restrict__ AHnext, int last)
{
    __shared__ short sh[2 * 128 * SA];
    short* As = sh;
    short* Bs = sh + 128 * SA;
    const int t = threadIdx.x;
    const int m0 = blockIdx.y * 128, n0 = blockIdx.x * 128;
    const int wave = t >> 6, lane = t & 63;
    const int wr = wave >> 1, wc = wave & 1;
    f32x4 acc[4][4] = {};
    for (int k0 = 0; k0 < 512; k0 += 32) {
#pragma unroll
        for (int i = 0; i < 2; ++i) {
            int idx = t + i * 256;
            int r = idx >> 2, c8 = (idx & 3) << 3;
            frag8 av = *reinterpret_cast<const frag8*>(A + (size_t)(m0 + r) * 512 + k0 + c8);
            *reinterpret_cast<frag8*>(&As[r * SA + c8]) = av;
            frag8 bv = *reinterpret_cast<const frag8*>(B + (size_t)(n0 + r) * 512 + k0 + c8);
            *reinterpret_cast<frag8*>(&Bs[r * SA + c8]) = bv;
        }
        __syncthreads();
        frag8 af[4], bfv[4];
#pragma unroll
        for (int f = 0; f < 4; ++f) {
            af[f]  = *reinterpret_cast<const frag8*>(&As[(wr * 64 + f * 16 + (lane & 15)) * SA + ((lane >> 4) << 3)]);
            bfv[f] = *reinterpret_cast<const frag8*>(&Bs[(wc * 64 + f * 16 + (lane & 15)) * SA + ((lane >> 4) << 3)]);
        }
#pragma unroll
        for (int fm = 0; fm < 4; ++fm)
#pragma unroll
            for (int fn = 0; fn < 4; ++fn)
                acc[fm][fn] = __builtin_amdgcn_mfma_f32_16x16x32_bf16(af[fm], bfv[fn], acc[fm][fn], 0, 0, 0);
        __syncthreads();
    }

    // epilogue: thread's 4 fn-fragments = gates i,f,g,o of unit j
    const int v = lane & 15;
    const int j = ((blockIdx.x * 2 + wc) << 4) + v;   // unit 0..511
    float bv0 = bias2[n0 + wc * 64 + 0 * 16 + v];
    float bv1 = bias2[n0 + wc * 64 + 1 * 16 + v];
    float bv2 = bias2[n0 + wc * 64 + 2 * 16 + v];
    float bv3 = bias2[n0 + wc * 64 + 3 * 16 + v];
#pragma unroll
    for (int fm = 0; fm < 4; ++fm) {
        int rowb = m0 + wr * 64 + fm * 16 + ((lane >> 4) << 2);
#pragma unroll
        for (int jr = 0; jr < 4; ++jr) {
            int row = rowb + jr;
            float gi = acc[fm][0][jr] + bv0;
            float gf = acc[fm][1][jr] + bv1;
            float gg = acc[fm][2][jr] + bv2;
            float go = acc[fm][3][jr] + bv3;
            size_t cidx = (size_t)row * 512 + j;
            float cn = sigm(gf) * cbuf[cidx] + sigm(gi) * tanhf(gg);
            cbuf[cidx] = cn;
            float hc = sigm(go) * tanhf(cn);
            if (j < 256) {
                float hv = enc[(size_t)row * 256 + j] + hc;
                AHnext[(size_t)row * 512 + 256 + j] = f2bf(hv);
                if (last) hbuf[(size_t)row * 256 + j] = hv;
            }
        }
    }
}

// ---------------- neigh (GCN attention + gate) ----------------

__global__ __launch_bounds__(128) void k_neigh(
    const int* __restrict__ conns, const int* __restrict__ deg,
    const int* __restrict__ ids2, int side,
    const float* __restrict__ emb, const short* __restrict__ T,
    const float* __restrict__ cg_W1, const float* __restrict__ cg_b1,
    const float* __restrict__ cg_ln_g, const float* __restrict__ cg_ln_b,
    const float* __restrict__ cg_W2, const float* __restrict__ cg_b2,
    const float* __restrict__ temp_p,
    float* __restrict__ outv, short* __restrict__ outbf,
    int out_row_off)
{
    int n = blockIdx.x;
    int t = threadIdx.x;  // 128
    __shared__ float proj[KN * 129];
    __shared__ float se[128];
    __shared__ int rels[KN], ents[KN];
    __shared__ float wts[KN];
    __shared__ float aggs[128];
    __shared__ float gate_s;

    int self_id = ids2[n * 2 + side];
    float self_e = emb[(size_t)self_id * 128 + t];
    se[t] = self_e;
    if (t < KN) {
        rels[t] = conns[((size_t)n * KN + t) * 2];
        ents[t] = conns[((size_t)n * KN + t) * 2 + 1];
    }
    __syncthreads();

#pragma unroll 2
    for (int k = 0; k < KN; ++k) {
        int r = rels[k], e = ents[k];
        float raw = bf2f(T[(size_t)r * 256 + t]) + bf2f(T[(size_t)e * 256 + 128 + t]);
        float p = raw > 0.f ? raw : 0.01f * raw;
        proj[k * 129 + t] = p;
    }
    __syncthreads();

    float sc = -1e9f;
    if (t < KN) {
        float s = 0.f;
        const float* pr = &proj[t * 129];
        for (int d = 0; d < 128; ++d) s += pr[d] * se[d];
        sc = (rels[t] == PAD_IDX) ? -1e9f : s;
    }
    if (t < 64) {
        float m = sc;
        for (int o = 32; o; o >>= 1) m = fmaxf(m, __shfl_xor(m, o));
        float e = (t < KN) ? __expf(sc - m) : 0.f;
        float ssum = e;
        for (int o = 32; o; o >>= 1) ssum += __shfl_xor(ssum, o);
        if (t < KN) wts[t] = e / ssum;
    }
    __syncthreads();

    float agg = 0.f;
    for (int k = 0; k < KN; ++k) agg += wts[k] * proj[k * 129 + t];
    aggs[t] = agg;
    __syncthreads();

    if (t < 64) {
        const float* w1 = cg_W1 + t * 128;
        float acc = cg_b1[t];
        for (int d = 0; d < 128; ++d) acc += aggs[d] * w1[d];
        float s = acc;
        for (int o = 32; o; o >>= 1) s += __shfl_xor(s, o);
        float mean = s * (1.f / 64.f);
        float dv = acc - mean;
        float vs = dv * dv;
        for (int o = 32; o; o >>= 1) vs += __shfl_xor(vs, o);
        float var = vs * (1.f / 64.f);
        float hv = dv * rsqrtf(var + 1e-5f) * cg_ln_g[t] + cg_ln_b[t];
        hv = fmaxf(hv, 0.f);
        float lg = hv * cg_W2[t];
        for (int o = 32; o; o >>= 1) lg += __shfl_xor(lg, o);
        if (t == 0) {
            lg += cg_b2[0];
            float temp = fminf(fmaxf(temp_p[0], 0.1f), 5.0f);
            float gate = sigm(lg / temp);
            gate_s = (deg[n] > 0) ? gate : 0.f;
        }
    }
    __syncthreads();

    float o = tanhf(self_e + gate_s * agg);
    size_t off = (size_t)(out_row_off + n) * 256 + (size_t)side * 128 + t;
    outv[off] = o;
    outbf[off] = f2bf(o);
}

// ---------------- LN (+residual); writes bf16 into both AH buffers ----------------

__global__ void k_ln(const float* __restrict__ se2out, const float* __restrict__ x,
                     const float* __restrict__ g, const float* __restrict__ b,
                     float* __restrict__ enc, short* __restrict__ AHa,
                     short* __restrict__ AHb, int M) {
    int wave = threadIdx.x >> 6, lane = threadIdx.x & 63;
    int row = blockIdx.x * 4 + wave;
    if (row >= M) return;
    const float* pr = se2out + (size_t)row * 256;
    const float* px = x + (size_t)row * 256;
    float v[4];
    float s = 0.f;
#pragma unroll
    for (int i = 0; i < 4; ++i) { v[i] = pr[lane + 64 * i] + px[lane + 64 * i]; s += v[i]; }
    for (int o = 32; o; o >>= 1) s += __shfl_xor(s, o);
    float mean = s * (1.f / 256.f);
    float vs = 0.f;
#pragma unroll
    for (int i = 0; i < 4; ++i) { float d = v[i] - mean; vs += d * d; }
    for (int o = 32; o; o >>= 1) vs += __shfl_xor(vs, o);
    float inv = rsqrtf(vs * (1.f / 256.f) + 1e-5f);
#pragma unroll
    for (int i = 0; i < 4; ++i) {
        int col = lane + 64 * i;
        float ov = (v[i] - mean) * inv * g[col] + b[col];
        enc[(size_t)row * 256 + col] = ov;
        if (row < 4096) {
            short bf = f2bf(ov);
            AHa[(size_t)row * 512 + col] = bf;
            AHb[(size_t)row * 512 + col] = bf;
        }
    }
}

__global__ void k_supportg(const float* __restrict__ enc, float* __restrict__ gout) {
    int j = threadIdx.x;  // 256
    float s = 0.f;
    for (int i = 0; i < 5; ++i) s += enc[(size_t)(4096 + i) * 256 + j];
    gout[j] = s * 0.2f;
}

// permuted biases: bias2_a[c]=bih[n]+bhh[n]; bias2_b[c]=...+dot(g, Whh[n][256:])
__global__ void k_whhbias(const float* __restrict__ gvec, const float* __restrict__ Whh,
                          const float* __restrict__ bih, const float* __restrict__ bhh,
                          float* __restrict__ bias_a, float* __restrict__ bias_b) {
    int c = blockIdx.x * 256 + threadIdx.x;
    if (c < 2048) {
        int n = lstm_perm(c);
        const float* wr = Whh + (size_t)n * 512 + 256;
        float s = 0.f;
        for (int q = 0; q < 256; ++q) s += gvec[q] * wr[q];
        float ba = bih[n] + bhh[n];
        bias_a[c] = ba;
        bias_b[c] = ba + s;
    }
}

__global__ void k_dot(const float* __restrict__ h, const float* __restrict__ gvec,
                      float* __restrict__ out) {
    int wave = threadIdx.x >> 6, lane = threadIdx.x & 63;
    int n = blockIdx.x * 4 + wave;
    if (n >= 4096) return;
    const float* p = h + (size_t)n * 256;
    float s = 0.f;
#pragma unroll
    for (int i = 0; i < 4; ++i) s += p[lane + 64 * i] * gvec[lane + 64 * i];
    for (int o = 32; o; o >>= 1) s += __shfl_xor(s, o);
    if (!lane) out[n] = s;
}

// ---------------- launch ----------------

extern "C" void kernel_launch(void* const* d_in, const int* in_sizes, int n_in,
                              void* d_out, int out_size, void* d_ws, size_t ws_size,
                              hipStream_t stream) {
    const int* query     = (const int*)d_in[0];
    const int* support   = (const int*)d_in[1];
    const int* q_l1      = (const int*)d_in[2];
    const int* q_deg_l   = (const int*)d_in[3];
    const int* q_r1      = (const int*)d_in[4];
    const int* q_deg_r   = (const int*)d_in[5];
    const int* s_l1      = (const int*)d_in[6];
    const int* s_deg_l   = (const int*)d_in[7];
    const int* s_r1      = (const int*)d_in[8];
    const int* s_deg_r   = (const int*)d_in[9];
    const float* emb     = (const float*)d_in[10];
    const float* gcn_W   = (const float*)d_in[11];
    const float* gcn_lin_b = (const float*)d_in[12];
    const float* gcn_b   = (const float*)d_in[13];
    const float* gate_temp = (const float*)d_in[14];
    const float* cg_W1   = (const float*)d_in[15];
    const float* cg_b1   = (const float*)d_in[16];
    const float* cg_ln_g = (const float*)d_in[17];
    const float* cg_ln_b = (const float*)d_in[18];
    const float* cg_W2   = (const float*)d_in[19];
    const float* cg_b2   = (const float*)d_in[20];
    const float* se_W1   = (const float*)d_in[21];
    const float* se_b1   = (const float*)d_in[22];
    const float* se_W2   = (const float*)d_in[23];
    const float* se_b2   = (const float*)d_in[24];
    const float* se_ln_g = (const float*)d_in[25];
    const float* se_ln_b = (const float*)d_in[26];
    const float* lstm_Wih = (const float*)d_in[27];
    const float* lstm_Whh = (const float*)d_in[28];
    const float* lstm_bih = (const float*)d_in[29];
    const float* lstm_bhh = (const float*)d_in[30];

    char* ws = (char*)d_ws;
    // overlay region (shares space with the 102.4 MB table T, dead after neigh)
    short* T       = (short*)(ws + 0);              // 200001*256*2 = 102,400,512
    short* h1bf    = (short*)(ws + 0);              // 4101*512*2   = 4,199,424
    float* se2out  = (float*)(ws + 4199424);        // 4101*256*4   = 4,199,424
    float* enc     = (float*)(ws + 8398848);        // 4101*256*4   = 4,199,424
    float* cbuf    = (float*)(ws + 12598272);       // 4096*512*4   = 8,388,608
    float* hbuf    = (float*)(ws + 20986880);       // 4096*256*4   = 4,194,304
    short* AHa     = (short*)(ws + 25181184);       // 4096*512*2   = 4,194,304
    short* AHb     = (short*)(ws + 29375488);       // 4096*512*2   = 4,194,304
    // persistent region after the table
    float* qsvec   = (float*)(ws + 102400512);      // 4101*256*4
    short* qsbf    = (short*)(ws + 106599936);      // 4101*256*2
    short* Bmat    = (short*)(ws + 108699648);      // 256*128*2
    float* bias256 = (float*)(ws + 108765184);      // 1024
    short* sw1     = (short*)(ws + 108766208);      // 512*256*2
    short* sw2     = (short*)(ws + 109028352);      // 256*512*2
    short* Bcomb   = (short*)(ws + 109290496);      // 2048*512*2
    float* sg      = (float*)(ws + 111387648);      // 1024
    float* bias_a  = (float*)(ws + 111388672);      // 8192
    float* bias_b  = (float*)(ws + 111396864);      // 8192
    float* outp    = (float*)d_out;

    hipMemsetAsync(AHa, 0, (size_t)4096 * 512 * 2, stream);
    hipMemsetAsync(cbuf, 0, (size_t)4096 * 512 * 4, stream);

    k_cast_bf16<<<512, 256, 0, stream>>>(se_W1, sw1, 512 * 256);
    k_cast_bf16<<<512, 256, 0, stream>>>(se_W2, sw2, 256 * 512);
    k_build_bmat<<<128, 256, 0, stream>>>(gcn_W, gcn_lin_b, gcn_b, Bmat, bias256);
    k_build_bcomb<<<4096, 256, 0, stream>>>(lstm_Wih, lstm_Whh, Bcomb);

    // T = emb @ [W1|W2]^T + bias256   (M=200001, N=256, K=128)
    gemm_bt<false, true, float><<<dim3(2, 1563), 256, 0, stream>>>(
        emb, 128, Bmat, 128, nullptr, T, 256, bias256, 200001, 256, 128);

    // neigh: q left/right, s left/right
    k_neigh<<<4096, 128, 0, stream>>>(q_l1, q_deg_l, query, 0, emb, T,
        cg_W1, cg_b1, cg_ln_g, cg_ln_b, cg_W2, cg_b2, gate_temp, qsvec, qsbf, 0);
    k_neigh<<<4096, 128, 0, stream>>>(q_r1, q_deg_r, query, 1, emb, T,
        cg_W1, cg_b1, cg_ln_g, cg_ln_b, cg_W2, cg_b2, gate_temp, qsvec, qsbf, 0);
    k_neigh<<<5, 128, 0, stream>>>(s_l1, s_deg_l, support, 0, emb, T,
        cg_W1, cg_b1, cg_ln_g, cg_ln_b, cg_W2, cg_b2, gate_temp, qsvec, qsbf, 4096);
    k_neigh<<<5, 128, 0, stream>>>(s_r1, s_deg_r, support, 1, emb, T,
        cg_W1, cg_b1, cg_ln_g, cg_ln_b, cg_W2, cg_b2, gate_temp, qsvec, qsbf, 4096);

    // support_enc
    gemm_bt<true, true, short><<<dim3(4, 33), 256, 0, stream>>>(
        qsbf, 256, sw1, 256, nullptr, h1bf, 512, se_b1, 4101, 512, 256);
    gemm_bt<false, false, short><<<dim3(2, 33), 256, 0, stream>>>(
        h1bf, 512, sw2, 512, se2out, nullptr, 256, se_b2, 4101, 256, 512);
    k_ln<<<1026, 256, 0, stream>>>(se2out, qsvec, se_ln_g, se_ln_b, enc, AHa, AHb, 4101);

    k_supportg<<<1, 256, 0, stream>>>(enc, sg);
    k_whhbias<<<8, 256, 0, stream>>>(sg, lstm_Whh, lstm_bih, lstm_bhh, bias_a, bias_b);

    // 4 fused LSTM steps (AH double-buffered: a->b->a->b->a)
    short* cur = AHa;
    short* nxt = AHb;
    for (int s = 0; s < 4; ++s) {
        gemm_lstm<<<dim3(16, 32), 256, 0, stream>>>(
            cur, Bcomb, s ? bias_b : bias_a, cbuf, enc, hbuf, nxt, s == 3);
        short* tmp = cur; cur = nxt; nxt = tmp;
    }

    k_dot<<<1024, 256, 0, stream>>>(hbuf, sg, outp);
}

// Round 4
// 305.493 us; speedup vs baseline: 1.5133x; 1.3949x over previous
//
#include <hip/hip_runtime.h>
#include <hip/hip_bf16.h>
#include <cstdint>
#include <cstddef>

#define PAD_IDX 200000
#define KN 50
#define MROWS 200001

using frag8 = __attribute__((ext_vector_type(8))) short;
using f32x4 = __attribute__((ext_vector_type(4))) float;

__device__ __forceinline__ short f2bf_rn(float v) {
    __hip_bfloat16 h = __float2bfloat16(v);
    union { __hip_bfloat16 h; short s; } u; u.h = h; return u.s;
}
__device__ __forceinline__ float bf2f(short s) {
    union { uint32_t u; float f; } x; x.u = ((uint32_t)(uint16_t)s) << 16;
    return x.f;
}
__device__ __forceinline__ float sigm(float x) { return 1.f / (1.f + __expf(-x)); }

__device__ __forceinline__ int lstm_perm(int c) {
    int u = c >> 6, g = (c >> 4) & 3, v = c & 15;
    return (g << 9) + (u << 4) + v;
}

// ---------------- fused prep: sw1, sw2, Bmat+bias256, Bcomb ----------------
__global__ void k_prep(const float* __restrict__ se_W1, const float* __restrict__ se_W2,
                       const float* __restrict__ gcn_W, const float* __restrict__ lin_b,
                       const float* __restrict__ gb,
                       const float* __restrict__ Wih, const float* __restrict__ Whh,
                       short* __restrict__ sw1, short* __restrict__ sw2,
                       short* __restrict__ Bmat, float* __restrict__ bias256,
                       short* __restrict__ Bcomb) {
    int b = blockIdx.x, t = threadIdx.x;
    if (b < 512) {
        int i = b * 256 + t;
        sw1[i] = f2bf_rn(se_W1[i]);
    } else if (b < 1024) {
        int i = (b - 512) * 256 + t;
        sw2[i] = f2bf_rn(se_W2[i]);
    } else if (b < 1152) {
        int i = (b - 1024) * 256 + t;
        int n = i >> 7, k = i & 127;
        float v = (n < 128) ? gcn_W[n * 256 + k] : gcn_W[(n - 128) * 256 + 128 + k];
        Bmat[i] = f2bf_rn(v);
        if (k == 0) bias256[n] = (n < 128) ? 0.f : (lin_b[n - 128] + gb[n - 128]);
    } else {
        int i = (b - 1152) * 256 + t;   // 0 .. 2048*512
        int c = i >> 9, k = i & 511;
        int n = lstm_perm(c);
        float v = (k < 256) ? Wih[n * 256 + k] : Whh[(size_t)n * 512 + (k - 256)];
        Bcomb[i] = f2bf_rn(v);
    }
}

// ---------------- streaming table kernel ----------------
// T[m, n0:n0+128] = emb[m,:] @ Bmat[n0:n0+128,:]^T + bias256 ; barrier-free tile loop.
// grid (2, 400), block 256 (4 waves x 32 rows).

__global__ __launch_bounds__(256, 2) void k_table(
    const float* __restrict__ emb, const short* __restrict__ Bmat,
    const float* __restrict__ bias256, short* __restrict__ T)
{
    __shared__ short Bs[128 * 136];   // 34.8 KB: B stage, then per-wave C bounce
    const int t = threadIdx.x, lane = t & 63, w = t >> 6;
    const int n0 = blockIdx.x * 128;
    const int l15 = lane & 15, lk = lane >> 4;

    // stage B half-panel (128 n x 128 k)
#pragma unroll
    for (int i = 0; i < 8; ++i) {
        int c = i * 256 + t;
        int row = c >> 4, k8 = (c & 15) << 3;
        *reinterpret_cast<frag8*>(&Bs[row * 136 + k8]) =
            *reinterpret_cast<const frag8*>(Bmat + (n0 + row) * 128 + k8);
    }
    __syncthreads();

    // hoist all B fragments to registers (tile-invariant)
    frag8 bq[8][4];
#pragma unroll
    for (int fn = 0; fn < 8; ++fn)
#pragma unroll
        for (int kf = 0; kf < 4; ++kf)
            bq[fn][kf] = *reinterpret_cast<const frag8*>(
                &Bs[(fn * 16 + l15) * 136 + kf * 32 + (lk << 3)]);
    float bc[8];
#pragma unroll
    for (int fn = 0; fn < 8; ++fn) bc[fn] = bias256[n0 + fn * 16 + l15];
    __syncthreads();   // all waves done reading Bs; it becomes the bounce buffer

    const int rbase = w * 32;
    for (int tile = blockIdx.y; tile < 1563; tile += gridDim.y) {
        const int m0 = tile * 128;
        f32x4 acc[2][8] = {};
#pragma unroll
        for (int kf = 0; kf < 4; ++kf) {
            frag8 af[2];
#pragma unroll
            for (int fm = 0; fm < 2; ++fm) {
                int row = m0 + rbase + fm * 16 + l15;
                frag8 av = {0, 0, 0, 0, 0, 0, 0, 0};
                if (row < MROWS) {
                    const float* p = emb + (size_t)row * 128 + kf * 32 + (lk << 3);
                    float4 v0 = *reinterpret_cast<const float4*>(p);
                    float4 v1 = *reinterpret_cast<const float4*>(p + 4);
                    av[0] = f2bf_rn(v0.x); av[1] = f2bf_rn(v0.y);
                    av[2] = f2bf_rn(v0.z); av[3] = f2bf_rn(v0.w);
                    av[4] = f2bf_rn(v1.x); av[5] = f2bf_rn(v1.y);
                    av[6] = f2bf_rn(v1.z); av[7] = f2bf_rn(v1.w);
                }
                af[fm] = av;
            }
#pragma unroll
            for (int fn = 0; fn < 8; ++fn) {
                acc[0][fn] = __builtin_amdgcn_mfma_f32_16x16x32_bf16(af[0], bq[fn][kf], acc[0][fn], 0, 0, 0);
                acc[1][fn] = __builtin_amdgcn_mfma_f32_16x16x32_bf16(af[1], bq[fn][kf], acc[1][fn], 0, 0, 0);
            }
        }
        // wave-private bounce (rows rbase..rbase+32 of Bs) -> coalesced stores
#pragma unroll
        for (int fm = 0; fm < 2; ++fm)
#pragma unroll
            for (int fn = 0; fn < 8; ++fn)
#pragma unroll
                for (int j = 0; j < 4; ++j) {
                    int lrow = rbase + fm * 16 + (lk << 2) + j;
                    Bs[lrow * 136 + fn * 16 + l15] = f2bf_rn(acc[fm][fn][j] + bc[fn]);
                }
#pragma unroll
        for (int p = 0; p < 8; ++p) {
            int idx = p * 64 + lane;
            int rl = idx >> 4, ch = idx & 15;
            int srow = rbase + rl;
            int grow = m0 + srow;
            if (grow < MROWS) {
                frag8 v = *reinterpret_cast<const frag8*>(&Bs[srow * 136 + ch * 8]);
                *reinterpret_cast<frag8*>(T + (size_t)grow * 256 + n0 + ch * 8) = v;
            }
        }
    }
}

// ---------------- generic MFMA GEMM (support_enc): C = A@B^T (+bias) ----------------

constexpr int SA = 40;
constexpr int CS = 132;

template<bool RELU, bool OUTBF>
__global__ __launch_bounds__(256) void gemm_bt(
    const short* __restrict__ A, int lda, const short* __restrict__ B, int ldb,
    float* __restrict__ C, short* __restrict__ Cbf, int ldc,
    const float* __restrict__ bias, int M, int N, int K)
{
    __shared__ short sh[2 * 128 * SA];
    short* As = sh;
    short* Bs = sh + 128 * SA;
    const int t = threadIdx.x;
    const int m0 = blockIdx.y * 128, n0 = blockIdx.x * 128;
    const int wave = t >> 6, lane = t & 63;
    const int wr = wave >> 1, wc = wave & 1;
    f32x4 acc[4][4] = {};
    for (int k0 = 0; k0 < K; k0 += 32) {
#pragma unroll
        for (int i = 0; i < 2; ++i) {
            int idx = t + i * 256;
            int r = idx >> 2, c8 = (idx & 3) << 3;
            frag8 av = {0, 0, 0, 0, 0, 0, 0, 0};
            int arow = m0 + r;
            if (arow < M)
                av = *reinterpret_cast<const frag8*>(A + (size_t)arow * lda + k0 + c8);
            *reinterpret_cast<frag8*>(&As[r * SA + c8]) = av;
            frag8 bv = *reinterpret_cast<const frag8*>(B + (size_t)(n0 + r) * ldb + k0 + c8);
            *reinterpret_cast<frag8*>(&Bs[r * SA + c8]) = bv;
        }
        __syncthreads();
        frag8 af[4], bfv[4];
#pragma unroll
        for (int f = 0; f < 4; ++f) {
            af[f]  = *reinterpret_cast<const frag8*>(&As[(wr * 64 + f * 16 + (lane & 15)) * SA + ((lane >> 4) << 3)]);
            bfv[f] = *reinterpret_cast<const frag8*>(&Bs[(wc * 64 + f * 16 + (lane & 15)) * SA + ((lane >> 4) << 3)]);
        }
#pragma unroll
        for (int fm = 0; fm < 4; ++fm)
#pragma unroll
            for (int fn = 0; fn < 4; ++fn)
                acc[fm][fn] = __builtin_amdgcn_mfma_f32_16x16x32_bf16(af[fm], bfv[fn], acc[fm][fn], 0, 0, 0);
        __syncthreads();
    }

    if constexpr (OUTBF) {
#pragma unroll
        for (int half = 0; half < 2; ++half) {
            if (wr == half) {
#pragma unroll
                for (int fm = 0; fm < 4; ++fm) {
                    int rl = fm * 16 + ((lane >> 4) << 2);
#pragma unroll
                    for (int fn = 0; fn < 4; ++fn) {
                        int col = wc * 64 + fn * 16 + (lane & 15);
                        float bcv = bias[n0 + col];
#pragma unroll
                        for (int j = 0; j < 4; ++j) {
                            float v = acc[fm][fn][j] + bcv;
                            if (RELU) v = fmaxf(v, 0.f);
                            sh[(rl + j) * CS + col] = f2bf_rn(v);
                        }
                    }
                }
            }
            __syncthreads();
#pragma unroll
            for (int p = 0; p < 4; ++p) {
                int off16 = p * 256 + t;
                int rl = off16 >> 4, ch = off16 & 15;
                int rr = m0 + half * 64 + rl;
                if (rr < M) {
                    frag8 val = *reinterpret_cast<const frag8*>(&sh[rl * CS + ch * 8]);
                    *reinterpret_cast<frag8*>(&Cbf[(size_t)rr * ldc + n0 + ch * 8]) = val;
                }
            }
            __syncthreads();
        }
    } else {
#pragma unroll
        for (int fm = 0; fm < 4; ++fm) {
            int rowb = m0 + wr * 64 + fm * 16 + ((lane >> 4) << 2);
#pragma unroll
            for (int fn = 0; fn < 4; ++fn) {
                int col = n0 + wc * 64 + fn * 16 + (lane & 15);
                float bcv = bias[col];
#pragma unroll
                for (int j = 0; j < 4; ++j) {
                    int rr = rowb + j;
                    if (rr < M) {
                        float v = acc[fm][fn][j] + bcv;
                        if (RELU) v = fmaxf(v, 0.f);
                        C[(size_t)rr * ldc + col] = v;
                    }
                }
            }
        }
    }
}

// ---------------- fused LSTM-step GEMM ----------------

__global__ __launch_bounds__(256) void gemm_lstm(
    const short* __restrict__ A, const short* __restrict__ B,
    const float* __restrict__ bias2, float* __restrict__ cbuf,
    const float* __restrict__ enc, float* __restrict__ hbuf,
    short* __restrict__ AHnext, int last)
{
    __shared__ short sh[2 * 128 * SA];
    short* As = sh;
    short* Bs = sh + 128 * SA;
    const int t = threadIdx.x;
    const int m0 = blockIdx.y * 128, n0 = blockIdx.x * 128;
    const int wave = t >> 6, lane = t & 63;
    const int wr = wave >> 1, wc = wave & 1;
    f32x4 acc[4][4] = {};
    for (int k0 = 0; k0 < 512; k0 += 32) {
#pragma unroll
        for (int i = 0; i < 2; ++i) {
            int idx = t + i * 256;
            int r = idx >> 2, c8 = (idx & 3) << 3;
            frag8 av = *reinterpret_cast<const frag8*>(A + (size_t)(m0 + r) * 512 + k0 + c8);
            *reinterpret_cast<frag8*>(&As[r * SA + c8]) = av;
            frag8 bv = *reinterpret_cast<const frag8*>(B + (size_t)(n0 + r) * 512 + k0 + c8);
            *reinterpret_cast<frag8*>(&Bs[r * SA + c8]) = bv;
        }
        __syncthreads();
        frag8 af[4], bfv[4];
#pragma unroll
        for (int f = 0; f < 4; ++f) {
            af[f]  = *reinterpret_cast<const frag8*>(&As[(wr * 64 + f * 16 + (lane & 15)) * SA + ((lane >> 4) << 3)]);
            bfv[f] = *reinterpret_cast<const frag8*>(&Bs[(wc * 64 + f * 16 + (lane & 15)) * SA + ((lane >> 4) << 3)]);
        }
#pragma unroll
        for (int fm = 0; fm < 4; ++fm)
#pragma unroll
            for (int fn = 0; fn < 4; ++fn)
                acc[fm][fn] = __builtin_amdgcn_mfma_f32_16x16x32_bf16(af[fm], bfv[fn], acc[fm][fn], 0, 0, 0);
        __syncthreads();
    }

    const int v = lane & 15;
    const int j = ((blockIdx.x * 2 + wc) << 4) + v;
    float bv0 = bias2[n0 + wc * 64 + 0 * 16 + v];
    float bv1 = bias2[n0 + wc * 64 + 1 * 16 + v];
    float bv2 = bias2[n0 + wc * 64 + 2 * 16 + v];
    float bv3 = bias2[n0 + wc * 64 + 3 * 16 + v];
#pragma unroll
    for (int fm = 0; fm < 4; ++fm) {
        int rowb = m0 + wr * 64 + fm * 16 + ((lane >> 4) << 2);
#pragma unroll
        for (int jr = 0; jr < 4; ++jr) {
            int row = rowb + jr;
            float gi = acc[fm][0][jr] + bv0;
            float gf = acc[fm][1][jr] + bv1;
            float gg = acc[fm][2][jr] + bv2;
            float go = acc[fm][3][jr] + bv3;
            size_t cidx = (size_t)row * 512 + j;
            float cn = sigm(gf) * cbuf[cidx] + sigm(gi) * tanhf(gg);
            cbuf[cidx] = cn;
            float hc = sigm(go) * tanhf(cn);
            if (j < 256) {
                float hv = enc[(size_t)row * 256 + j] + hc;
                AHnext[(size_t)row * 512 + 256 + j] = f2bf_rn(hv);
                if (last) hbuf[(size_t)row * 256 + j] = hv;
            }
        }
    }
}

// ---------------- fused neigh (all 4 cases in one launch) ----------------

constexpr int PS = 132;  // proj row stride (floats), 16B aligned

__global__ __launch_bounds__(128) void k_neigh(
    const int* __restrict__ q_l1, const int* __restrict__ q_deg_l,
    const int* __restrict__ q_r1, const int* __restrict__ q_deg_r,
    const int* __restrict__ s_l1, const int* __restrict__ s_deg_l,
    const int* __restrict__ s_r1, const int* __restrict__ s_deg_r,
    const int* __restrict__ query, const int* __restrict__ support,
    const float* __restrict__ emb, const short* __restrict__ T,
    const float* __restrict__ cg_W1, const float* __restrict__ cg_b1,
    const float* __restrict__ cg_ln_g, const float* __restrict__ cg_ln_b,
    const float* __restrict__ cg_W2, const float* __restrict__ cg_b2,
    const float* __restrict__ temp_p,
    float* __restrict__ outv, short* __restrict__ outbf)
{
    int b = blockIdx.x;
    const int* conns; const int* deg; const int* ids2; int side, n, orow;
    if (b < 4096)      { conns = q_l1; deg = q_deg_l; ids2 = query;   side = 0; n = b;        orow = n; }
    else if (b < 8192) { conns = q_r1; deg = q_deg_r; ids2 = query;   side = 1; n = b - 4096; orow = n; }
    else if (b < 8197) { conns = s_l1; deg = s_deg_l; ids2 = support; side = 0; n = b - 8192; orow = 4096 + n; }
    else               { conns = s_r1; deg = s_deg_r; ids2 = support; side = 1; n = b - 8197; orow = 4096 + n; }

    int t = threadIdx.x;  // 128
    __shared__ __align__(16) float proj[KN * PS];
    __shared__ __align__(16) float se[128];
    __shared__ int rels[KN], ents[KN];
    __shared__ float wts[KN];
    __shared__ __align__(16) float aggs[128];
    __shared__ float gate_s;

    int self_id = ids2[n * 2 + side];
    float self_e = emb[(size_t)self_id * 128 + t];
    se[t] = self_e;
    if (t < KN) {
        rels[t] = conns[((size_t)n * KN + t) * 2];
        ents[t] = conns[((size_t)n * KN + t) * 2 + 1];
    }
    __syncthreads();

#pragma unroll 5
    for (int k = 0; k < KN; ++k) {
        int r = rels[k], e = ents[k];
        float raw = bf2f(T[(size_t)r * 256 + t]) + bf2f(T[(size_t)e * 256 + 128 + t]);
        float p = raw > 0.f ? raw : 0.01f * raw;
        proj[k * PS + t] = p;
    }
    __syncthreads();

    float sc = -1e9f;
    if (t < KN) {
        const float4* pr = reinterpret_cast<const float4*>(&proj[t * PS]);
        const float4* se4 = reinterpret_cast<const float4*>(se);
        float s = 0.f;
#pragma unroll 8
        for (int d = 0; d < 32; ++d) {
            float4 a = pr[d], bb = se4[d];
            s += a.x * bb.x + a.y * bb.y + a.z * bb.z + a.w * bb.w;
        }
        sc = (rels[t] == PAD_IDX) ? -1e9f : s;
    }
    if (t < 64) {
        float m = sc;
        for (int o = 32; o; o >>= 1) m = fmaxf(m, __shfl_xor(m, o));
        float e = (t < KN) ? __expf(sc - m) : 0.f;
        float ssum = e;
        for (int o = 32; o; o >>= 1) ssum += __shfl_xor(ssum, o);
        if (t < KN) wts[t] = e / ssum;
    }
    __syncthreads();

    float agg = 0.f;
#pragma unroll 5
    for (int k = 0; k < KN; ++k) agg += wts[k] * proj[k * PS + t];
    aggs[t] = agg;
    __syncthreads();

    if (t < 64) {
        const float4* w1 = reinterpret_cast<const float4*>(cg_W1 + t * 128);
        const float4* a4 = reinterpret_cast<const float4*>(aggs);
        float acc = cg_b1[t];
#pragma unroll 8
        for (int d = 0; d < 32; ++d) {
            float4 a = a4[d], ww = w1[d];
            acc += a.x * ww.x + a.y * ww.y + a.z * ww.z + a.w * ww.w;
        }
        float s = acc;
        for (int o = 32; o; o >>= 1) s += __shfl_xor(s, o);
        float mean = s * (1.f / 64.f);
        float dv = acc - mean;
        float vs = dv * dv;
        for (int o = 32; o; o >>= 1) vs += __shfl_xor(vs, o);
        float var = vs * (1.f / 64.f);
        float hv = dv * rsqrtf(var + 1e-5f) * cg_ln_g[t] + cg_ln_b[t];
        hv = fmaxf(hv, 0.f);
        float lg = hv * cg_W2[t];
        for (int o = 32; o; o >>= 1) lg += __shfl_xor(lg, o);
        if (t == 0) {
            lg += cg_b2[0];
            float temp = fminf(fmaxf(temp_p[0], 0.1f), 5.0f);
            float gate = sigm(lg / temp);
            gate_s = (deg[n] > 0) ? gate : 0.f;
        }
    }
    __syncthreads();

    float o = tanhf(self_e + gate_s * agg);
    size_t off = (size_t)orow * 256 + (size_t)side * 128 + t;
    outv[off] = o;
    outbf[off] = f2bf_rn(o);
}

// ---------------- LN (+residual) ----------------

__global__ void k_ln(const float* __restrict__ se2out, const float* __restrict__ x,
                     const float* __restrict__ g, const float* __restrict__ b,
                     float* __restrict__ enc, short* __restrict__ AHa,
                     short* __restrict__ AHb, int M) {
    int wave = threadIdx.x >> 6, lane = threadIdx.x & 63;
    int row = blockIdx.x * 4 + wave;
    if (row >= M) return;
    const float* pr = se2out + (size_t)row * 256;
    const float* px = x + (size_t)row * 256;
    float v[4];
    float s = 0.f;
#pragma unroll
    for (int i = 0; i < 4; ++i) { v[i] = pr[lane + 64 * i] + px[lane + 64 * i]; s += v[i]; }
    for (int o = 32; o; o >>= 1) s += __shfl_xor(s, o);
    float mean = s * (1.f / 256.f);
    float vs = 0.f;
#pragma unroll
    for (int i = 0; i < 4; ++i) { float d = v[i] - mean; vs += d * d; }
    for (int o = 32; o; o >>= 1) vs += __shfl_xor(vs, o);
    float inv = rsqrtf(vs * (1.f / 256.f) + 1e-5f);
#pragma unroll
    for (int i = 0; i < 4; ++i) {
        int col = lane + 64 * i;
        float ov = (v[i] - mean) * inv * g[col] + b[col];
        enc[(size_t)row * 256 + col] = ov;
        if (row < 4096) {
            short bf = f2bf_rn(ov);
            AHa[(size_t)row * 512 + col] = bf;
            AHb[(size_t)row * 512 + col] = bf;
        }
    }
}

// ---------------- support mean + permuted LSTM biases (fused) ----------------

__global__ void k_whhbias(const float* __restrict__ enc, const float* __restrict__ Whh,
                          const float* __restrict__ bih, const float* __restrict__ bhh,
                          float* __restrict__ sg, float* __restrict__ bias_a,
                          float* __restrict__ bias_b) {
    __shared__ __align__(16) float sgs[256];
    int t = threadIdx.x;
    float s0 = 0.f;
#pragma unroll
    for (int i = 0; i < 5; ++i) s0 += enc[(size_t)(4096 + i) * 256 + t];
    s0 *= 0.2f;
    sgs[t] = s0;
    if (blockIdx.x == 0) sg[t] = s0;
    __syncthreads();

    int c = blockIdx.x * 256 + t;
    int nn = lstm_perm(c);
    const float4* wr = reinterpret_cast<const float4*>(Whh + (size_t)nn * 512 + 256);
    const float4* g4 = reinterpret_cast<const float4*>(sgs);
    float s = 0.f;
#pragma unroll 8
    for (int q = 0; q < 64; ++q) {
        float4 a = g4[q], ww = wr[q];
        s += a.x * ww.x + a.y * ww.y + a.z * ww.z + a.w * ww.w;
    }
    float ba = bih[nn] + bhh[nn];
    bias_a[c] = ba;
    bias_b[c] = ba + s;
}

__global__ void k_dot(const float* __restrict__ h, const float* __restrict__ gvec,
                      float* __restrict__ out) {
    int wave = threadIdx.x >> 6, lane = threadIdx.x & 63;
    int n = blockIdx.x * 4 + wave;
    if (n >= 4096) return;
    const float* p = h + (size_t)n * 256;
    float s = 0.f;
#pragma unroll
    for (int i = 0; i < 4; ++i) s += p[lane + 64 * i] * gvec[lane + 64 * i];
    for (int o = 32; o; o >>= 1) s += __shfl_xor(s, o);
    if (!lane) out[n] = s;
}

// ---------------- launch ----------------

extern "C" void kernel_launch(void* const* d_in, const int* in_sizes, int n_in,
                              void* d_out, int out_size, void* d_ws, size_t ws_size,
                              hipStream_t stream) {
    const int* query     = (const int*)d_in[0];
    const int* support   = (const int*)d_in[1];
    const int* q_l1      = (const int*)d_in[2];
    const int* q_deg_l   = (const int*)d_in[3];
    const int* q_r1      = (const int*)d_in[4];
    const int* q_deg_r   = (const int*)d_in[5];
    const int* s_l1      = (const int*)d_in[6];
    const int* s_deg_l   = (const int*)d_in[7];
    const int* s_r1      = (const int*)d_in[8];
    const int* s_deg_r   = (const int*)d_in[9];
    const float* emb     = (const float*)d_in[10];
    const float* gcn_W   = (const float*)d_in[11];
    const float* gcn_lin_b = (const float*)d_in[12];
    const float* gcn_b   = (const float*)d_in[13];
    const float* gate_temp = (const float*)d_in[14];
    const float* cg_W1   = (const float*)d_in[15];
    const float* cg_b1   = (const float*)d_in[16];
    const float* cg_ln_g = (const float*)d_in[17];
    const float* cg_ln_b = (const float*)d_in[18];
    const float* cg_W2   = (const float*)d_in[19];
    const float* cg_b2   = (const float*)d_in[20];
    const float* se_W1   = (const float*)d_in[21];
    const float* se_b1   = (const float*)d_in[22];
    const float* se_W2   = (const float*)d_in[23];
    const float* se_b2   = (const float*)d_in[24];
    const float* se_ln_g = (const float*)d_in[25];
    const float* se_ln_b = (const float*)d_in[26];
    const float* lstm_Wih = (const float*)d_in[27];
    const float* lstm_Whh = (const float*)d_in[28];
    const float* lstm_bih = (const float*)d_in[29];
    const float* lstm_bhh = (const float*)d_in[30];

    char* ws = (char*)d_ws;
    short* T       = (short*)(ws + 0);              // 200001*256*2 = 102,400,512
    short* h1bf    = (short*)(ws + 0);              // overlay after neigh
    float* se2out  = (float*)(ws + 4199424);
    float* enc     = (float*)(ws + 8398848);
    float* cbuf    = (float*)(ws + 12598272);
    float* hbuf    = (float*)(ws + 20986880);
    short* AHa     = (short*)(ws + 25181184);
    short* AHb     = (short*)(ws + 29375488);
    float* qsvec   = (float*)(ws + 102400512);
    short* qsbf    = (short*)(ws + 106599936);
    short* Bmat    = (short*)(ws + 108699648);
    float* bias256 = (float*)(ws + 108765184);
    short* sw1     = (short*)(ws + 108766208);
    short* sw2     = (short*)(ws + 109028352);
    short* Bcomb   = (short*)(ws + 109290496);
    float* sg      = (float*)(ws + 111387648);
    float* bias_a  = (float*)(ws + 111388672);
    float* bias_b  = (float*)(ws + 111396864);
    float* outp    = (float*)d_out;

    hipMemsetAsync(AHa, 0, (size_t)4096 * 512 * 2, stream);
    hipMemsetAsync(cbuf, 0, (size_t)4096 * 512 * 4, stream);

    k_prep<<<5248, 256, 0, stream>>>(se_W1, se_W2, gcn_W, gcn_lin_b, gcn_b,
                                     lstm_Wih, lstm_Whh, sw1, sw2, Bmat, bias256, Bcomb);

    k_table<<<dim3(2, 400), 256, 0, stream>>>(emb, Bmat, bias256, T);

    k_neigh<<<8202, 128, 0, stream>>>(q_l1, q_deg_l, q_r1, q_deg_r,
        s_l1, s_deg_l, s_r1, s_deg_r, query, support, emb, T,
        cg_W1, cg_b1, cg_ln_g, cg_ln_b, cg_W2, cg_b2, gate_temp, qsvec, qsbf);

    gemm_bt<true, true><<<dim3(4, 33), 256, 0, stream>>>(
        qsbf, 256, sw1, 256, nullptr, h1bf, 512, se_b1, 4101, 512, 256);
    gemm_bt<false, false><<<dim3(2, 33), 256, 0, stream>>>(
        h1bf, 512, sw2, 512, se2out, nullptr, 256, se_b2, 4101, 256, 512);
    k_ln<<<1026, 256, 0, stream>>>(se2out, qsvec, se_ln_g, se_ln_b, enc, AHa, AHb, 4101);

    k_whhbias<<<8, 256, 0, stream>>>(enc, lstm_Whh, lstm_bih, lstm_bhh, sg, bias_a, bias_b);

    short* cur = AHa;
    short* nxt = AHb;
    for (int s = 0; s < 4; ++s) {
        gemm_lstm<<<dim3(16, 32), 256, 0, stream>>>(
            cur, Bcomb, s ? bias_b : bias_a, cbuf, enc, hbuf, nxt, s == 3);
        short* tmp = cur; cur = nxt; nxt = tmp;
    }

    k_dot<<<1024, 256, 0, stream>>>(hbuf, sg, outp);
}

// Round 5
// 269.670 us; speedup vs baseline: 1.7144x; 1.1328x over previous
//
#include <hip/hip_runtime.h>
#include <hip/hip_bf16.h>
#include <cstdint>
#include <cstddef>

#define PAD_IDX 200000
#define KN 50
#define MROWS 200001

using frag8 = __attribute__((ext_vector_type(8))) short;
using f32x4 = __attribute__((ext_vector_type(4))) float;

__device__ __forceinline__ short f2bf_rn(float v) {
    __hip_bfloat16 h = __float2bfloat16(v);
    union { __hip_bfloat16 h; short s; } u; u.h = h; return u.s;
}
__device__ __forceinline__ float bf2f(short s) {
    union { uint32_t u; float f; } x; x.u = ((uint32_t)(uint16_t)s) << 16;
    return x.f;
}
__device__ __forceinline__ float sigm(float x) { return 1.f / (1.f + __expf(-x)); }

__device__ __forceinline__ int lstm_perm(int c) {
    int u = c >> 6, g = (c >> 4) & 3, v = c & 15;
    return (g << 9) + (u << 4) + v;
}

// ---------------- fused prep: sw1, sw2, Bmat+bias256, Bih_perm, Bhh_perm ----------------
__global__ void k_prep(const float* __restrict__ se_W1, const float* __restrict__ se_W2,
                       const float* __restrict__ gcn_W, const float* __restrict__ lin_b,
                       const float* __restrict__ gb,
                       const float* __restrict__ Wih, const float* __restrict__ Whh,
                       short* __restrict__ sw1, short* __restrict__ sw2,
                       short* __restrict__ Bmat, float* __restrict__ bias256,
                       short* __restrict__ Bih, short* __restrict__ Bhh) {
    int b = blockIdx.x, t = threadIdx.x;
    if (b < 512) {
        int i = b * 256 + t;
        sw1[i] = f2bf_rn(se_W1[i]);
    } else if (b < 1024) {
        int i = (b - 512) * 256 + t;
        sw2[i] = f2bf_rn(se_W2[i]);
    } else if (b < 1152) {
        int i = (b - 1024) * 256 + t;
        int n = i >> 7, k = i & 127;
        float v = (n < 128) ? gcn_W[n * 256 + k] : gcn_W[(n - 128) * 256 + 128 + k];
        Bmat[i] = f2bf_rn(v);
        if (k == 0) bias256[n] = (n < 128) ? 0.f : (lin_b[n - 128] + gb[n - 128]);
    } else {
        int i = (b - 1152) * 256 + t;   // 0 .. 2048*512
        int c = i >> 9, k = i & 511;
        int n = lstm_perm(c);
        if (k < 256) Bih[c * 256 + k] = f2bf_rn(Wih[n * 256 + k]);
        else         Bhh[c * 256 + (k - 256)] = f2bf_rn(Whh[(size_t)n * 512 + (k - 256)]);
    }
}

// ---------------- streaming table kernel ----------------
// T[m, n0:n0+128] = emb[m,:] @ Bmat[n0:n0+128,:]^T + bias256 ; barrier-free tile loop.

__global__ __launch_bounds__(256, 2) void k_table(
    const float* __restrict__ emb, const short* __restrict__ Bmat,
    const float* __restrict__ bias256, short* __restrict__ T)
{
    __shared__ short Bs[128 * 136];
    const int t = threadIdx.x, lane = t & 63, w = t >> 6;
    const int n0 = blockIdx.x * 128;
    const int l15 = lane & 15, lk = lane >> 4;

#pragma unroll
    for (int i = 0; i < 8; ++i) {
        int c = i * 256 + t;
        int row = c >> 4, k8 = (c & 15) << 3;
        *reinterpret_cast<frag8*>(&Bs[row * 136 + k8]) =
            *reinterpret_cast<const frag8*>(Bmat + (n0 + row) * 128 + k8);
    }
    __syncthreads();

    frag8 bq[8][4];
#pragma unroll
    for (int fn = 0; fn < 8; ++fn)
#pragma unroll
        for (int kf = 0; kf < 4; ++kf)
            bq[fn][kf] = *reinterpret_cast<const frag8*>(
                &Bs[(fn * 16 + l15) * 136 + kf * 32 + (lk << 3)]);
    float bc[8];
#pragma unroll
    for (int fn = 0; fn < 8; ++fn) bc[fn] = bias256[n0 + fn * 16 + l15];
    __syncthreads();

    const int rbase = w * 32;
    for (int tile = blockIdx.y; tile < 1563; tile += gridDim.y) {
        const int m0 = tile * 128;
        f32x4 acc[2][8] = {};
#pragma unroll
        for (int kf = 0; kf < 4; ++kf) {
            frag8 af[2];
#pragma unroll
            for (int fm = 0; fm < 2; ++fm) {
                int row = m0 + rbase + fm * 16 + l15;
                frag8 av = {0, 0, 0, 0, 0, 0, 0, 0};
                if (row < MROWS) {
                    const float* p = emb + (size_t)row * 128 + kf * 32 + (lk << 3);
                    float4 v0 = *reinterpret_cast<const float4*>(p);
                    float4 v1 = *reinterpret_cast<const float4*>(p + 4);
                    av[0] = f2bf_rn(v0.x); av[1] = f2bf_rn(v0.y);
                    av[2] = f2bf_rn(v0.z); av[3] = f2bf_rn(v0.w);
                    av[4] = f2bf_rn(v1.x); av[5] = f2bf_rn(v1.y);
                    av[6] = f2bf_rn(v1.z); av[7] = f2bf_rn(v1.w);
                }
                af[fm] = av;
            }
#pragma unroll
            for (int fn = 0; fn < 8; ++fn) {
                acc[0][fn] = __builtin_amdgcn_mfma_f32_16x16x32_bf16(af[0], bq[fn][kf], acc[0][fn], 0, 0, 0);
                acc[1][fn] = __builtin_amdgcn_mfma_f32_16x16x32_bf16(af[1], bq[fn][kf], acc[1][fn], 0, 0, 0);
            }
        }
#pragma unroll
        for (int fm = 0; fm < 2; ++fm)
#pragma unroll
            for (int fn = 0; fn < 8; ++fn)
#pragma unroll
                for (int j = 0; j < 4; ++j) {
                    int lrow = rbase + fm * 16 + (lk << 2) + j;
                    Bs[lrow * 136 + fn * 16 + l15] = f2bf_rn(acc[fm][fn][j] + bc[fn]);
                }
#pragma unroll
        for (int p = 0; p < 8; ++p) {
            int idx = p * 64 + lane;
            int rl = idx >> 4, ch = idx & 15;
            int srow = rbase + rl;
            int grow = m0 + srow;
            if (grow < MROWS) {
                frag8 v = *reinterpret_cast<const frag8*>(&Bs[srow * 136 + ch * 8]);
                *reinterpret_cast<frag8*>(T + (size_t)grow * 256 + n0 + ch * 8) = v;
            }
        }
    }
}

// ---------------- generic MFMA GEMM: C = A@B^T (+bias) ----------------

constexpr int SA = 40;
constexpr int CS = 132;

template<bool RELU, bool OUTBF>
__global__ __launch_bounds__(256) void gemm_bt(
    const short* __restrict__ A, int lda, const short* __restrict__ B, int ldb,
    float* __restrict__ C, short* __restrict__ Cbf, int ldc,
    const float* __restrict__ bias, int M, int N, int K)
{
    __shared__ short sh[2 * 128 * SA];
    short* As = sh;
    short* Bs = sh + 128 * SA;
    const int t = threadIdx.x;
    const int m0 = blockIdx.y * 128, n0 = blockIdx.x * 128;
    const int wave = t >> 6, lane = t & 63;
    const int wr = wave >> 1, wc = wave & 1;
    f32x4 acc[4][4] = {};
    for (int k0 = 0; k0 < K; k0 += 32) {
#pragma unroll
        for (int i = 0; i < 2; ++i) {
            int idx = t + i * 256;
            int r = idx >> 2, c8 = (idx & 3) << 3;
            frag8 av = {0, 0, 0, 0, 0, 0, 0, 0};
            int arow = m0 + r;
            if (arow < M)
                av = *reinterpret_cast<const frag8*>(A + (size_t)arow * lda + k0 + c8);
            *reinterpret_cast<frag8*>(&As[r * SA + c8]) = av;
            frag8 bv = *reinterpret_cast<const frag8*>(B + (size_t)(n0 + r) * ldb + k0 + c8);
            *reinterpret_cast<frag8*>(&Bs[r * SA + c8]) = bv;
        }
        __syncthreads();
        frag8 af[4], bfv[4];
#pragma unroll
        for (int f = 0; f < 4; ++f) {
            af[f]  = *reinterpret_cast<const frag8*>(&As[(wr * 64 + f * 16 + (lane & 15)) * SA + ((lane >> 4) << 3)]);
            bfv[f] = *reinterpret_cast<const frag8*>(&Bs[(wc * 64 + f * 16 + (lane & 15)) * SA + ((lane >> 4) << 3)]);
        }
#pragma unroll
        for (int fm = 0; fm < 4; ++fm)
#pragma unroll
            for (int fn = 0; fn < 4; ++fn)
                acc[fm][fn] = __builtin_amdgcn_mfma_f32_16x16x32_bf16(af[fm], bfv[fn], acc[fm][fn], 0, 0, 0);
        __syncthreads();
    }

    if constexpr (OUTBF) {
#pragma unroll
        for (int half = 0; half < 2; ++half) {
            if (wr == half) {
#pragma unroll
                for (int fm = 0; fm < 4; ++fm) {
                    int rl = fm * 16 + ((lane >> 4) << 2);
#pragma unroll
                    for (int fn = 0; fn < 4; ++fn) {
                        int col = wc * 64 + fn * 16 + (lane & 15);
                        float bcv = bias[n0 + col];
#pragma unroll
                        for (int j = 0; j < 4; ++j) {
                            float v = acc[fm][fn][j] + bcv;
                            if (RELU) v = fmaxf(v, 0.f);
                            sh[(rl + j) * CS + col] = f2bf_rn(v);
                        }
                    }
                }
            }
            __syncthreads();
#pragma unroll
            for (int p = 0; p < 4; ++p) {
                int off16 = p * 256 + t;
                int rl = off16 >> 4, ch = off16 & 15;
                int rr = m0 + half * 64 + rl;
                if (rr < M) {
                    frag8 val = *reinterpret_cast<const frag8*>(&sh[rl * CS + ch * 8]);
                    *reinterpret_cast<frag8*>(&Cbf[(size_t)rr * ldc + n0 + ch * 8]) = val;
                }
            }
            __syncthreads();
        }
    } else {
#pragma unroll
        for (int fm = 0; fm < 4; ++fm) {
            int rowb = m0 + wr * 64 + fm * 16 + ((lane >> 4) << 2);
#pragma unroll
            for (int fn = 0; fn < 4; ++fn) {
                int col = n0 + wc * 64 + fn * 16 + (lane & 15);
                float bcv = bias[col];
#pragma unroll
                for (int j = 0; j < 4; ++j) {
                    int rr = rowb + j;
                    if (rr < M) {
                        float v = acc[fm][fn][j] + bcv;
                        if (RELU) v = fmaxf(v, 0.f);
                        C[(size_t)rr * ldc + col] = v;
                    }
                }
            }
        }
    }
}

// ---------------- LSTM steps 1-3: acc = h @ Bhh^T ; epilogue adds G0 + whh_r, cell update ----------------
// A points at AHcur + 256 (h half, lda=512). K=256. grid (16, 32).

__global__ __launch_bounds__(256) void gemm_lstm2(
    const short* __restrict__ A, const short* __restrict__ Bp,
    const float* __restrict__ G0, const float* __restrict__ whh_r,
    float* __restrict__ cbuf, const float* __restrict__ enc,
    float* __restrict__ hbuf, short* __restrict__ AHnext, int last)
{
    __shared__ short sh[2 * 128 * SA];
    short* As = sh;
    short* Bs = sh + 128 * SA;
    const int t = threadIdx.x;
    const int m0 = blockIdx.y * 128, n0 = blockIdx.x * 128;
    const int wave = t >> 6, lane = t & 63;
    const int wr = wave >> 1, wc = wave & 1;
    f32x4 acc[4][4] = {};
    for (int k0 = 0; k0 < 256; k0 += 32) {
#pragma unroll
        for (int i = 0; i < 2; ++i) {
            int idx = t + i * 256;
            int r = idx >> 2, c8 = (idx & 3) << 3;
            frag8 av = *reinterpret_cast<const frag8*>(A + (size_t)(m0 + r) * 512 + k0 + c8);
            *reinterpret_cast<frag8*>(&As[r * SA + c8]) = av;
            frag8 bv = *reinterpret_cast<const frag8*>(Bp + (size_t)(n0 + r) * 256 + k0 + c8);
            *reinterpret_cast<frag8*>(&Bs[r * SA + c8]) = bv;
        }
        __syncthreads();
        frag8 af[4], bfv[4];
#pragma unroll
        for (int f = 0; f < 4; ++f) {
            af[f]  = *reinterpret_cast<const frag8*>(&As[(wr * 64 + f * 16 + (lane & 15)) * SA + ((lane >> 4) << 3)]);
            bfv[f] = *reinterpret_cast<const frag8*>(&Bs[(wc * 64 + f * 16 + (lane & 15)) * SA + ((lane >> 4) << 3)]);
        }
#pragma unroll
        for (int fm = 0; fm < 4; ++fm)
#pragma unroll
            for (int fn = 0; fn < 4; ++fn)
                acc[fm][fn] = __builtin_amdgcn_mfma_f32_16x16x32_bf16(af[fm], bfv[fn], acc[fm][fn], 0, 0, 0);
        __syncthreads();
    }

    const int v = lane & 15;
    const int colbase = n0 + wc * 64;
    const int j = ((blockIdx.x * 2 + wc) << 4) + v;   // unit 0..511
    float wr0 = whh_r[colbase + v];
    float wr1 = whh_r[colbase + 16 + v];
    float wr2 = whh_r[colbase + 32 + v];
    float wr3 = whh_r[colbase + 48 + v];
#pragma unroll
    for (int fm = 0; fm < 4; ++fm) {
        int rowb = m0 + wr * 64 + fm * 16 + ((lane >> 4) << 2);
#pragma unroll
        for (int jr = 0; jr < 4; ++jr) {
            int row = rowb + jr;
            const float* g0p = G0 + (size_t)row * 2048 + colbase;
            float gi = acc[fm][0][jr] + g0p[v]      + wr0;
            float gf = acc[fm][1][jr] + g0p[16 + v] + wr1;
            float gg = acc[fm][2][jr] + g0p[32 + v] + wr2;
            float go = acc[fm][3][jr] + g0p[48 + v] + wr3;
            size_t cidx = (size_t)row * 512 + j;
            float cn = sigm(gf) * cbuf[cidx] + sigm(gi) * tanhf(gg);
            cbuf[cidx] = cn;
            float hc = sigm(go) * tanhf(cn);
            if (j < 256) {
                float hv = enc[(size_t)row * 256 + j] + hc;
                AHnext[(size_t)row * 512 + 256 + j] = f2bf_rn(hv);
                if (last) hbuf[(size_t)row * 256 + j] = hv;
            }
        }
    }
}

// ---------------- LSTM step 0 (c_prev = 0): pure elementwise over G0 ----------------

__global__ void k_lstm0(const float* __restrict__ G0, float* __restrict__ cbuf,
                        const float* __restrict__ enc, short* __restrict__ AHnext) {
    int idx = blockIdx.x * 256 + threadIdx.x;  // 4096*512
    int row = idx >> 9, j = idx & 511;
    int u = j >> 4, v = j & 15;
    const float* gp = G0 + (size_t)row * 2048 + (u << 6);
    float gi = gp[v], gg = gp[32 + v], go = gp[48 + v];
    float cn = sigm(gi) * tanhf(gg);
    cbuf[idx] = cn;
    float hc = sigm(go) * tanhf(cn);
    if (j < 256) {
        float hv = enc[(size_t)row * 256 + j] + hc;
        AHnext[(size_t)row * 512 + 256 + j] = f2bf_rn(hv);
    }
}

// ---------------- fused neigh (bf16 proj in LDS, high occupancy) ----------------

constexpr int PS2 = 136;  // proj row stride in shorts (272 B, 16B-aligned)

__global__ __launch_bounds__(128) void k_neigh(
    const int* __restrict__ q_l1, const int* __restrict__ q_deg_l,
    const int* __restrict__ q_r1, const int* __restrict__ q_deg_r,
    const int* __restrict__ s_l1, const int* __restrict__ s_deg_l,
    const int* __restrict__ s_r1, const int* __restrict__ s_deg_r,
    const int* __restrict__ query, const int* __restrict__ support,
    const float* __restrict__ emb, const short* __restrict__ T,
    const float* __restrict__ cg_W1, const float* __restrict__ cg_b1,
    const float* __restrict__ cg_ln_g, const float* __restrict__ cg_ln_b,
    const float* __restrict__ cg_W2, const float* __restrict__ cg_b2,
    const float* __restrict__ temp_p,
    float* __restrict__ outv, short* __restrict__ outbf)
{
    int b = blockIdx.x;
    const int* conns; const int* deg; const int* ids2; int side, n, orow;
    if (b < 4096)      { conns = q_l1; deg = q_deg_l; ids2 = query;   side = 0; n = b;        orow = n; }
    else if (b < 8192) { conns = q_r1; deg = q_deg_r; ids2 = query;   side = 1; n = b - 4096; orow = n; }
    else if (b < 8197) { conns = s_l1; deg = s_deg_l; ids2 = support; side = 0; n = b - 8192; orow = 4096 + n; }
    else               { conns = s_r1; deg = s_deg_r; ids2 = support; side = 1; n = b - 8197; orow = 4096 + n; }

    int t = threadIdx.x;  // 128
    __shared__ __align__(16) short projb[KN * PS2];   // 13.6 KB (bf16)
    __shared__ __align__(16) float se[128];
    __shared__ int rels[KN], ents[KN];
    __shared__ float wts[KN];
    __shared__ float scs[KN];
    __shared__ __align__(16) float aggs[128];
    __shared__ float gate_s;

    int self_id = ids2[n * 2 + side];
    float self_e = emb[(size_t)self_id * 128 + t];
    se[t] = self_e;
    if (t < KN) {
        rels[t] = conns[((size_t)n * KN + t) * 2];
        ents[t] = conns[((size_t)n * KN + t) * 2 + 1];
    }
    __syncthreads();

#pragma unroll 10
    for (int k = 0; k < KN; ++k) {
        int r = rels[k], e = ents[k];
        float raw = bf2f(T[(size_t)r * 256 + t]) + bf2f(T[(size_t)e * 256 + 128 + t]);
        float p = raw > 0.f ? raw : 0.01f * raw;
        projb[k * PS2 + t] = f2bf_rn(p);
    }
    __syncthreads();

    // score: 100 lanes, each pair (2k, 2k+1) computes half a 128-dot
    {
        int k = t >> 1, hf = t & 1;
        float s = 0.f;
        if (k < KN) {
            const short* pr = &projb[k * PS2 + hf * 64];
            const float* seh = &se[hf * 64];
#pragma unroll
            for (int i = 0; i < 8; ++i) {
                frag8 v = *reinterpret_cast<const frag8*>(pr + i * 8);
#pragma unroll
                for (int q = 0; q < 8; ++q) s += bf2f(v[q]) * seh[i * 8 + q];
            }
            s += __shfl_xor(s, 1);
            if (hf == 0) scs[k] = (rels[k] == PAD_IDX) ? -1e9f : s;
        }
    }
    __syncthreads();

    if (t < 64) {
        float sc = (t < KN) ? scs[t] : -1e9f;
        float m = sc;
        for (int o = 32; o; o >>= 1) m = fmaxf(m, __shfl_xor(m, o));
        float e = (t < KN) ? __expf(sc - m) : 0.f;
        float ssum = e;
        for (int o = 32; o; o >>= 1) ssum += __shfl_xor(ssum, o);
        if (t < KN) wts[t] = e / ssum;
    }
    __syncthreads();

    float agg = 0.f;
#pragma unroll 10
    for (int k = 0; k < KN; ++k) agg += wts[k] * bf2f(projb[k * PS2 + t]);
    aggs[t] = agg;
    __syncthreads();

    if (t < 64) {
        const float4* w1 = reinterpret_cast<const float4*>(cg_W1 + t * 128);
        const float4* a4 = reinterpret_cast<const float4*>(aggs);
        float acc = cg_b1[t];
#pragma unroll 8
        for (int d = 0; d < 32; ++d) {
            float4 a = a4[d], ww = w1[d];
            acc += a.x * ww.x + a.y * ww.y + a.z * ww.z + a.w * ww.w;
        }
        float s = acc;
        for (int o = 32; o; o >>= 1) s += __shfl_xor(s, o);
        float mean = s * (1.f / 64.f);
        float dv = acc - mean;
        float vs = dv * dv;
        for (int o = 32; o; o >>= 1) vs += __shfl_xor(vs, o);
        float var = vs * (1.f / 64.f);
        float hv = dv * rsqrtf(var + 1e-5f) * cg_ln_g[t] + cg_ln_b[t];
        hv = fmaxf(hv, 0.f);
        float lg = hv * cg_W2[t];
        for (int o = 32; o; o >>= 1) lg += __shfl_xor(lg, o);
        if (t == 0) {
            lg += cg_b2[0];
            float temp = fminf(fmaxf(temp_p[0], 0.1f), 5.0f);
            float gate = sigm(lg / temp);
            gate_s = (deg[n] > 0) ? gate : 0.f;
        }
    }
    __syncthreads();

    float o = tanhf(self_e + gate_s * agg);
    size_t off = (size_t)orow * 256 + (size_t)side * 128 + t;
    outv[off] = o;
    outbf[off] = f2bf_rn(o);
}

// ---------------- LN (+residual) ----------------

__global__ void k_ln(const float* __restrict__ se2out, const float* __restrict__ x,
                     const float* __restrict__ g, const float* __restrict__ b,
                     float* __restrict__ enc, short* __restrict__ AHa,
                     short* __restrict__ AHb, int M) {
    int wave = threadIdx.x >> 6, lane = threadIdx.x & 63;
    int row = blockIdx.x * 4 + wave;
    if (row >= M) return;
    const float* pr = se2out + (size_t)row * 256;
    const float* px = x + (size_t)row * 256;
    float v[4];
    float s = 0.f;
#pragma unroll
    for (int i = 0; i < 4; ++i) { v[i] = pr[lane + 64 * i] + px[lane + 64 * i]; s += v[i]; }
    for (int o = 32; o; o >>= 1) s += __shfl_xor(s, o);
    float mean = s * (1.f / 256.f);
    float vs = 0.f;
#pragma unroll
    for (int i = 0; i < 4; ++i) { float d = v[i] - mean; vs += d * d; }
    for (int o = 32; o; o >>= 1) vs += __shfl_xor(vs, o);
    float inv = rsqrtf(vs * (1.f / 256.f) + 1e-5f);
#pragma unroll
    for (int i = 0; i < 4; ++i) {
        int col = lane + 64 * i;
        float ov = (v[i] - mean) * inv * g[col] + b[col];
        enc[(size_t)row * 256 + col] = ov;
        if (row < 4096) {
            short bf = f2bf_rn(ov);
            AHa[(size_t)row * 512 + col] = bf;
            AHb[(size_t)row * 512 + col] = bf;
        }
    }
}

// ---------------- support mean + permuted LSTM biases ----------------

__global__ void k_whhbias(const float* __restrict__ enc, const float* __restrict__ Whh,
                          const float* __restrict__ bih, const float* __restrict__ bhh,
                          float* __restrict__ sg, float* __restrict__ bias_a,
                          float* __restrict__ whh_r) {
    __shared__ __align__(16) float sgs[256];
    int t = threadIdx.x;
    float s0 = 0.f;
#pragma unroll
    for (int i = 0; i < 5; ++i) s0 += enc[(size_t)(4096 + i) * 256 + t];
    s0 *= 0.2f;
    sgs[t] = s0;
    if (blockIdx.x == 0) sg[t] = s0;
    __syncthreads();

    int c = blockIdx.x * 256 + t;
    int nn = lstm_perm(c);
    const float4* wr = reinterpret_cast<const float4*>(Whh + (size_t)nn * 512 + 256);
    const float4* g4 = reinterpret_cast<const float4*>(sgs);
    float s = 0.f;
#pragma unroll 8
    for (int q = 0; q < 64; ++q) {
        float4 a = g4[q], ww = wr[q];
        s += a.x * ww.x + a.y * ww.y + a.z * ww.z + a.w * ww.w;
    }
    bias_a[c] = bih[nn] + bhh[nn];
    whh_r[c] = s;
}

__global__ void k_dot(const float* __restrict__ h, const float* __restrict__ gvec,
                      float* __restrict__ out) {
    int wave = threadIdx.x >> 6, lane = threadIdx.x & 63;
    int n = blockIdx.x * 4 + wave;
    if (n >= 4096) return;
    const float* p = h + (size_t)n * 256;
    float s = 0.f;
#pragma unroll
    for (int i = 0; i < 4; ++i) s += p[lane + 64 * i] * gvec[lane + 64 * i];
    for (int o = 32; o; o >>= 1) s += __shfl_xor(s, o);
    if (!lane) out[n] = s;
}

// ---------------- launch ----------------

extern "C" void kernel_launch(void* const* d_in, const int* in_sizes, int n_in,
                              void* d_out, int out_size, void* d_ws, size_t ws_size,
                              hipStream_t stream) {
    const int* query     = (const int*)d_in[0];
    const int* support   = (const int*)d_in[1];
    const int* q_l1      = (const int*)d_in[2];
    const int* q_deg_l   = (const int*)d_in[3];
    const int* q_r1      = (const int*)d_in[4];
    const int* q_deg_r   = (const int*)d_in[5];
    const int* s_l1      = (const int*)d_in[6];
    const int* s_deg_l   = (const int*)d_in[7];
    const int* s_r1      = (const int*)d_in[8];
    const int* s_deg_r   = (const int*)d_in[9];
    const float* emb     = (const float*)d_in[10];
    const float* gcn_W   = (const float*)d_in[11];
    const float* gcn_lin_b = (const float*)d_in[12];
    const float* gcn_b   = (const float*)d_in[13];
    const float* gate_temp = (const float*)d_in[14];
    const float* cg_W1   = (const float*)d_in[15];
    const float* cg_b1   = (const float*)d_in[16];
    const float* cg_ln_g = (const float*)d_in[17];
    const float* cg_ln_b = (const float*)d_in[18];
    const float* cg_W2   = (const float*)d_in[19];
    const float* cg_b2   = (const float*)d_in[20];
    const float* se_W1   = (const float*)d_in[21];
    const float* se_b1   = (const float*)d_in[22];
    const float* se_W2   = (const float*)d_in[23];
    const float* se_b2   = (const float*)d_in[24];
    const float* se_ln_g = (const float*)d_in[25];
    const float* se_ln_b = (const float*)d_in[26];
    const float* lstm_Wih = (const float*)d_in[27];
    const float* lstm_Whh = (const float*)d_in[28];
    const float* lstm_bih = (const float*)d_in[29];
    const float* lstm_bhh = (const float*)d_in[30];

    char* ws = (char*)d_ws;
    short* T       = (short*)(ws + 0);              // 200001*256*2 = 102,400,512 (dead after neigh)
    short* h1bf    = (short*)(ws + 0);              // overlay
    float* se2out  = (float*)(ws + 4199424);
    float* enc     = (float*)(ws + 8398848);
    float* cbuf    = (float*)(ws + 12598272);       // 4096*512*4
    float* hbuf    = (float*)(ws + 20986880);       // 4096*256*4
    short* AHa     = (short*)(ws + 25181184);       // 4096*512*2
    short* AHb     = (short*)(ws + 29375488);       // 4096*512*2
    float* G0      = (float*)(ws + 33569792);       // 4096*2048*4 = 33,554,432 (ends 67,124,224)
    float* qsvec   = (float*)(ws + 102400512);
    short* qsbf    = (short*)(ws + 106599936);
    short* Bmat    = (short*)(ws + 108699648);
    float* bias256 = (float*)(ws + 108765184);
    short* sw1     = (short*)(ws + 108766208);
    short* sw2     = (short*)(ws + 109028352);
    short* Bih     = (short*)(ws + 109290496);      // 2048*256*2 = 1,048,576
    short* Bhh     = (short*)(ws + 110339072);      // 2048*256*2
    float* sg      = (float*)(ws + 111387648);
    float* bias_a  = (float*)(ws + 111388672);
    float* whh_r   = (float*)(ws + 111396864);
    float* outp    = (float*)d_out;

    k_prep<<<5248, 256, 0, stream>>>(se_W1, se_W2, gcn_W, gcn_lin_b, gcn_b,
                                     lstm_Wih, lstm_Whh, sw1, sw2, Bmat, bias256, Bih, Bhh);

    k_table<<<dim3(2, 400), 256, 0, stream>>>(emb, Bmat, bias256, T);

    k_neigh<<<8202, 128, 0, stream>>>(q_l1, q_deg_l, q_r1, q_deg_r,
        s_l1, s_deg_l, s_r1, s_deg_r, query, support, emb, T,
        cg_W1, cg_b1, cg_ln_g, cg_ln_b, cg_W2, cg_b2, gate_temp, qsvec, qsbf);

    gemm_bt<true, true><<<dim3(4, 33), 256, 0, stream>>>(
        qsbf, 256, sw1, 256, nullptr, h1bf, 512, se_b1, 4101, 512, 256);
    gemm_bt<false, false><<<dim3(2, 33), 256, 0, stream>>>(
        h1bf, 512, sw2, 512, se2out, nullptr, 256, se_b2, 4101, 256, 512);
    k_ln<<<1026, 256, 0, stream>>>(se2out, qsvec, se_ln_g, se_ln_b, enc, AHa, AHb, 4101);

    k_whhbias<<<8, 256, 0, stream>>>(enc, lstm_Whh, lstm_bih, lstm_bhh, sg, bias_a, whh_r);

    // G0 = qenc @ Wih_perm^T + bias_a   (M=4096, N=2048, K=256)
    gemm_bt<false, false><<<dim3(16, 32), 256, 0, stream>>>(
        AHa, 512, Bih, 256, G0, nullptr, 2048, bias_a, 4096, 2048, 256);

    // step 0: elementwise (c=0); h -> AHb
    k_lstm0<<<8192, 256, 0, stream>>>(G0, cbuf, enc, AHb);

    // steps 1-3: K=256 GEMM + fused cell update (AHb -> AHa -> AHb -> AHa)
    gemm_lstm2<<<dim3(16, 32), 256, 0, stream>>>(
        AHb + 256, Bhh, G0, whh_r, cbuf, enc, hbuf, AHa, 0);
    gemm_lstm2<<<dim3(16, 32), 256, 0, stream>>>(
        AHa + 256, Bhh, G0, whh_r, cbuf, enc, hbuf, AHb, 0);
    gemm_lstm2<<<dim3(16, 32), 256, 0, stream>>>(
        AHb + 256, Bhh, G0, whh_r, cbuf, enc, hbuf, AHa, 1);

    k_dot<<<1024, 256, 0, stream>>>(hbuf, sg, outp);
}